// Round 20
// baseline (1052.611 us; speedup 1.0000x reference)
//
#include <hip/hip_runtime.h>
#include <hip/hip_bf16.h>
#include <math.h>

#define DEVI __device__ __forceinline__

static constexpr int BB = 32, NN = 2048, S1 = 512, S2 = 128;

typedef float f32x4 __attribute__((ext_vector_type(4)));
typedef short s16x8 __attribute__((ext_vector_type(8)));

// ---------------- static workspace layout (float units) ----------------
static constexpr size_t OFF_XS   = 0;
static constexpr size_t OFF_YS   = OFF_XS + (size_t)BB*NN;
static constexpr size_t OFF_ZS   = OFF_YS + (size_t)BB*NN;
static constexpr size_t OFF_SSQ  = OFF_ZS + (size_t)BB*NN;
static constexpr size_t OFF_NX1X = OFF_SSQ + (size_t)BB*NN;
static constexpr size_t OFF_NX1Y = OFF_NX1X + (size_t)BB*S1;
static constexpr size_t OFF_NX1Z = OFF_NX1Y + (size_t)BB*S1;
static constexpr size_t OFF_NX2X = OFF_NX1Z + (size_t)BB*S1;
static constexpr size_t OFF_NX2Y = OFF_NX2X + (size_t)BB*S2;
static constexpr size_t OFF_NX2Z = OFF_NX2Y + (size_t)BB*S2;
static constexpr size_t OFF_CODE = OFF_NX2Z + (size_t)BB*S2;          // (unused)
static constexpr size_t OFF_O3P  = OFF_CODE + (size_t)3*BB*512;
static constexpr size_t OFF_P1   = OFF_O3P + (size_t)3*BB*4*512;      // R24: bf16 (ushort), rows of 128
static constexpr size_t OFF_X3   = OFF_P1 + (size_t)3*BB*S1*128;      // reused: fps1 dd spill (BB*NN floats)
static constexpr size_t OFF_H3   = OFF_X3 + (size_t)3*BB*S2*260;     // (unused)
static constexpr size_t OFF_W    = OFF_H3 + (size_t)3*BB*S2*512;
static constexpr size_t W1A  = OFF_W;
static constexpr size_t B1A  = W1A + 3*64*6;
static constexpr size_t W2A  = B1A + 3*64;
static constexpr size_t B2A  = W2A + 3*128*64;
static constexpr size_t W1B  = B2A + 3*128;
static constexpr size_t B1B  = W1B + 3*128*132;
static constexpr size_t W2B  = B1B + 3*128;
static constexpr size_t B2B  = W2B + 3*256*128;
static constexpr size_t W1C  = B2B + 3*256;
static constexpr size_t B1C  = W1C + 3*512*260;
static constexpr size_t W2C  = B1C + 3*512;
static constexpr size_t B2C  = W2C + 3*512*512;
static constexpr size_t FW1  = B2C + 3*512;
static constexpr size_t FB1  = FW1 + 3*256*512;
static constexpr size_t FG1  = FB1 + 3*256;
static constexpr size_t FBE1 = FG1 + 3*256;
static constexpr size_t FW2  = FBE1 + 3*256;
static constexpr size_t FB2  = FW2 + 3*128*256;
static constexpr size_t FG2  = FB2 + 3*128;
static constexpr size_t FBE2 = FG2 + 3*128;
static constexpr size_t OFF_KNN1 = FBE2 + 3*128;
static constexpr size_t OFF_KNN2 = OFF_KNN1 + (size_t)BB*S1*16;
static constexpr size_t OFF_W1BF = OFF_KNN2 + (size_t)BB*S2*48;
static constexpr size_t OFF_W2BF = OFF_W1BF + 30720;
static constexpr size_t OFF_W1CBH = OFF_W2BF + 49152;
static constexpr size_t OFF_W1CBL = OFF_W1CBH + 221184;
static constexpr size_t OFF_W2CBH = OFF_W1CBL + 221184;
static constexpr size_t OFF_W2CBL = OFF_W2CBH + 393216;
static constexpr size_t OFF_X3BH  = OFF_W2CBL + 393216;
static constexpr size_t OFF_X3BL  = OFF_X3BH + 1769472;
static constexpr size_t OFF_H3BH  = OFF_X3BL + 1769472;
static constexpr size_t OFF_H3BL  = OFF_H3BH + 3145728;
static constexpr size_t OFF_W2ABH = OFF_H3BL + 3145728;
static constexpr size_t OFF_W2ABL = OFF_W2ABH + 12288;
static constexpr size_t WS_FLOATS = OFF_W2ABL + 12288;

__device__ __align__(16) float g_ws[WS_FLOATS];
__device__ int g_is_f32;
__device__ int g_flip;
__device__ int g_bad;
__device__ int g_nz;

DEVI float bf2f(const __hip_bfloat16 v){ return __bfloat162float(v); }
DEVI float rn_add(float a, float b){ return __fadd_rn(a,b); }
DEVI float rn_mul(float a, float b){ return __fmul_rn(a,b); }
DEVI float rn_sub(float a, float b){ return __fsub_rn(a,b); }
DEVI float sq3(float x,float y,float z){ return rn_add(rn_add(rn_mul(x,x),rn_mul(y,y)),rn_mul(z,z)); }

DEVI float ldany(const void* s, size_t i, int isf){
  return isf ? ((const float*)s)[i] : bf2f(((const __hip_bfloat16*)s)[i]);
}
DEVI unsigned short f2bf(float f){
  unsigned u = __float_as_uint(f);
  unsigned r = (u + 0x7FFFu + ((u>>16)&1u)) >> 16;
  return (unsigned short)r;
}
DEVI float bfbits2f(unsigned short h){ return __uint_as_float(((unsigned)h)<<16); }
DEVI void mfma16(f32x4& d, s16x8 a, s16x8 b){
  asm volatile("v_mfma_f32_16x16x32_bf16 %0, %1, %2, %0" : "+v"(d) : "v"(a), "v"(b));
}
DEVI void mfma_guard(f32x4& d){
  asm volatile("s_nop 7\n\ts_nop 7\n\ts_nop 2" : "+v"(d));
}

// DPP helpers (validated R12). old = self -> boundary lanes no-op.
#define DPPF(dst, src, CTRL) dst = __uint_as_float((unsigned)__builtin_amdgcn_update_dpp(\
    (int)__float_as_uint(src), (int)__float_as_uint(src), CTRL, 0xF, 0xF, false))
#define DPPI(dst, src, CTRL) dst = __builtin_amdgcn_update_dpp(src, src, CTRL, 0xF, 0xF, false)
#define RED_STEP(CTRL) { float ov; int oi; DPPF(ov, best, CTRL); DPPI(oi, bidx, CTRL); \
  if (ov > best || (ov == best && oi < bidx)){ best = ov; bidx = oi; } }
#define WAVE_ARGMAX() RED_STEP(0xB1) RED_STEP(0x4E) RED_STEP(0x124) RED_STEP(0x128) RED_STEP(0x142) RED_STEP(0x143)

// R20: DPP argmin (same validated ctrl sequence, predicate flipped). Result in lane 63.
#define REDMIN_STEP(CTRL) { float ov; int oi; DPPF(ov, best, CTRL); DPPI(oi, bidx, CTRL); \
  if (ov < best || (ov == best && oi < bidx)){ best = ov; bidx = oi; } }
#define WAVE_ARGMIN() REDMIN_STEP(0xB1) REDMIN_STEP(0x4E) REDMIN_STEP(0x124) REDMIN_STEP(0x128) REDMIN_STEP(0x142) REDMIN_STEP(0x143)

// ---------------- init + dtype detection ----------------
__global__ __launch_bounds__(256) void init_detect_kernel(const void* __restrict__ pc){
  __shared__ int s_cnt[256];
  int t = threadIdx.x;
  if (t==0){ g_flip=0; g_bad=0; g_nz=0; }
  const unsigned short* h = (const unsigned short*)pc;
  int weird = 0;
  for (int i=t; i<4096; i+=256){
    unsigned short v = h[2*i];
    int e = (v >> 7) & 0xFF;
    if (e == 0xFF || e < 90 || e > 140) weird++;
  }
  s_cnt[t] = weird; __syncthreads();
  for (int o=128;o>0;o>>=1){ if (t<o) s_cnt[t]+=s_cnt[t+o]; __syncthreads(); }
  if (t==0) g_is_f32 = (s_cnt[0] > 1024) ? 1 : 0;
}

// ---------------- fused param-convert + prep_xyz ----------------
struct ParamPtrs { const void* p[20]; };

DEVI void cvt_arr(const void* s, float* d, int n, int g, int gs, int isf){
  for (int i=g;i<n;i+=gs) d[i] = ldany(s,i,isf);
}
DEVI void cvt_pad(const void* s, float* d, int rows, int cin, int cinp, int g, int gs, int isf){
  int tot = rows*cinp;
  for (int i=g;i<tot;i+=gs){ int r=i/cinp, c=i%cinp; d[i] = (c<cin)? ldany(s,(size_t)r*cin+c,isf) : 0.f; }
}

// blocks 0-255: prep_xyz; blocks 256-767: cvt_params
__global__ __launch_bounds__(256) void cvtprep_kernel(ParamPtrs pp, const void* __restrict__ pc, int mode){
  if (mode==1 && g_flip==0) return;
  const int isf = g_is_f32 ^ mode;
  if (blockIdx.x < 256){
    int i = blockIdx.x*256 + threadIdx.x;
    int b = i >> 11, n = i & 2047;
    float x = ldany(pc, (size_t)(b*3+0)*2048 + n, isf);
    float y = ldany(pc, (size_t)(b*3+1)*2048 + n, isf);
    float z = ldany(pc, (size_t)(b*3+2)*2048 + n, isf);
    g_ws[OFF_XS+i]=x; g_ws[OFF_YS+i]=y; g_ws[OFF_ZS+i]=z;
    g_ws[OFF_SSQ+i]=sq3(x,y,z);
    return;
  }
  int g = (blockIdx.x-256)*256 + threadIdx.x; int gs = 512*256;
  float* ws = g_ws;
  cvt_arr(pp.p[0],  ws+W1A, 3*64*6, g, gs, isf);
  cvt_arr(pp.p[1],  ws+B1A, 3*64, g, gs, isf);
  cvt_arr(pp.p[2],  ws+W2A, 3*128*64, g, gs, isf);
  cvt_arr(pp.p[3],  ws+B2A, 3*128, g, gs, isf);
  cvt_pad(pp.p[4],  ws+W1B, 3*128, 131, 132, g, gs, isf);
  cvt_arr(pp.p[5],  ws+B1B, 3*128, g, gs, isf);
  cvt_arr(pp.p[6],  ws+W2B, 3*256*128, g, gs, isf);
  cvt_arr(pp.p[7],  ws+B2B, 3*256, g, gs, isf);
  cvt_pad(pp.p[8],  ws+W1C, 3*512, 259, 260, g, gs, isf);
  cvt_arr(pp.p[9],  ws+B1C, 3*512, g, gs, isf);
  cvt_arr(pp.p[10], ws+W2C, 3*512*512, g, gs, isf);
  cvt_arr(pp.p[11], ws+B2C, 3*512, g, gs, isf);
  cvt_arr(pp.p[12], ws+FW1, 3*256*512, g, gs, isf);
  cvt_arr(pp.p[13], ws+FB1, 3*256, g, gs, isf);
  cvt_arr(pp.p[14], ws+FG1, 3*256, g, gs, isf);
  cvt_arr(pp.p[15], ws+FBE1,3*256, g, gs, isf);
  cvt_arr(pp.p[16], ws+FW2, 3*128*256, g, gs, isf);
  cvt_arr(pp.p[17], ws+FB2, 3*128, g, gs, isf);
  cvt_arr(pp.p[18], ws+FG2, 3*128, g, gs, isf);
  cvt_arr(pp.p[19], ws+FBE2,3*128, g, gs, isf);
}

// ---------------- fused sanity scans (coords + FW1) ----------------
__global__ __launch_bounds__(256) void scan_check_kernel(){
  size_t off; int n, g, gs;
  if (blockIdx.x < 128){ off = OFF_XS; n = 3*BB*NN; g = blockIdx.x*256 + threadIdx.x; gs = 128*256; }
  else { off = FW1; n = 3*256*512; g = (blockIdx.x-128)*256 + threadIdx.x; gs = 128*256; }
  int bad=0, nz=0;
  for (int i=g;i<n;i+=gs){
    float v = g_ws[off + i];
    if (v != v || fabsf(v) > 1e4f) bad=1;
    if (fabsf(v) > 1e-20f) nz=1;
  }
  unsigned long long mb = __ballot(bad), mn = __ballot(nz);
  if ((threadIdx.x & 63)==0){
    if (mb) atomicOr(&g_bad, 1);
    if (mn) atomicOr(&g_nz, 1);
  }
}

__global__ __launch_bounds__(64) void resolve_flip_kernel(){
  if (threadIdx.x==0){
    g_flip = (g_bad || !g_nz) ? 1 : 0;
    g_bad = 0; g_nz = 0;
  }
}

// ---------------- bf16 weight conversion body ----------------
DEVI void cvt_bf16_body(int g, int gs){
  unsigned short* w1d = (unsigned short*)(g_ws + OFF_W1BF);
  for (int i=g; i<3*128*160; i+=gs){
    int br = i/(128*160); int rem = i%(128*160); int h = rem/160; int c = rem%160;
    float v = (c<132) ? g_ws[W1B + ((size_t)br*128 + h)*132 + c] : 0.f;
    w1d[i] = f2bf(v);
  }
  unsigned short* w2d = (unsigned short*)(g_ws + OFF_W2BF);
  for (int i=g; i<3*256*128; i+=gs) w2d[i] = f2bf(g_ws[W2B + i]);
  unsigned short* w1ch = (unsigned short*)(g_ws + OFF_W1CBH);
  unsigned short* w1cl = (unsigned short*)(g_ws + OFF_W1CBL);
  for (int i=g; i<3*512*288; i+=gs){
    int br = i/(512*288); int rem = i%(512*288); int n = rem/288; int c = rem%288;
    float v = (c<260) ? g_ws[W1C + ((size_t)br*512 + n)*260 + c] : 0.f;
    unsigned short hi = f2bf(v);
    w1ch[i] = hi; w1cl[i] = f2bf(v - bfbits2f(hi));
  }
  unsigned short* w2ch = (unsigned short*)(g_ws + OFF_W2CBH);
  unsigned short* w2cl = (unsigned short*)(g_ws + OFF_W2CBL);
  for (int i=g; i<3*512*512; i+=gs){
    float v = g_ws[W2C + i];
    unsigned short hi = f2bf(v);
    w2ch[i] = hi; w2cl[i] = f2bf(v - bfbits2f(hi));
  }
  unsigned short* w2ah = (unsigned short*)(g_ws + OFF_W2ABH);
  unsigned short* w2al = (unsigned short*)(g_ws + OFF_W2ABL);
  for (int i=g; i<3*128*64; i+=gs){
    float v = g_ws[W2A + i];
    unsigned short hi = f2bf(v);
    w2ah[i] = hi; w2al[i] = f2bf(v - bfbits2f(hi));
  }
}

// ---------------- FPS1 (R27: three-way split at iters 171/342, bit-exact dd carry) ----------------
static constexpr int SP1 = 171, SP2 = 342;

#define FPS_DECL(J) float px##J, py##J, pz##J, dd##J;
#define FPS_LD256A(J) { int n=(J)*256+t; px##J=xs[n]; py##J=ys[n]; pz##J=zs[n]; dd##J=1e10f; xl[n]=px##J; yl[n]=py##J; zl[n]=pz##J; }
#define FPS_LD256B(J) { int n=(J)*256+t; px##J=xs[n]; py##J=ys[n]; pz##J=zs[n]; dd##J=ddg[n]; xl[n]=px##J; yl[n]=py##J; zl[n]=pz##J; }
#define FPS_SAVE(J) ddg[(J)*256+t]=dd##J;
#define FPS_LD64(J) { int n=(J)*64+t; px##J=xs[n]; py##J=ys[n]; pz##J=zs[n]; dd##J=1e10f; xl[n]=px##J; yl[n]=py##J; zl[n]=pz##J; }
#define FPS_UPD(J) { float dx=rn_sub(px##J,lx), dy=rn_sub(py##J,ly), dz=rn_sub(pz##J,lz); float d=sq3(dx,dy,dz); dd##J=fminf(dd##J,d); }
#define FPS_T1(J,JA,JB) float v##J; int q##J; { bool c = dd##JB > dd##JA; v##J = c? dd##JB : dd##JA; q##J = c? (JB) : (JA); }
#define FPS_T2(JA,JB) { bool c = v##JB > v##JA; v##JA = c? v##JB : v##JA; q##JA = c? q##JB : q##JA; }

// R15-proven iteration body (4-wave parity combine + LDS gather), shared by all segments
#define FPS1_ITER_BODY() \
    FPS_UPD(0) FPS_UPD(1) FPS_UPD(2) FPS_UPD(3) FPS_UPD(4) FPS_UPD(5) FPS_UPD(6) FPS_UPD(7) \
    FPS_T1(0,0,1) FPS_T1(1,2,3) FPS_T1(2,4,5) FPS_T1(3,6,7) \
    FPS_T2(0,1) FPS_T2(2,3) \
    FPS_T2(0,2) \
    float best = v0; int bidx = q0*256 + t; \
    WAVE_ARGMAX() \
    int par = i & 1; \
    if ((t&63)==63){ s_val[par][wave]=best; s_idx[par][wave]=bidx; } \
    __syncthreads(); \
    float va = s_val[par][0], vb = s_val[par][1], vc = s_val[par][2], vd = s_val[par][3]; \
    int ia = s_idx[par][0], ib = s_idx[par][1], ic = s_idx[par][2], id_ = s_idx[par][3]; \
    if (vb > va || (vb == va && ib < ia)){ va = vb; ia = ib; } \
    if (vd > vc || (vd == vc && id_ < ic)){ vc = vd; ic = id_; } \
    if (vc > va || (vc == va && ic < ia)){ va = vc; ia = ic; } \
    int gidx = ia; \
    lx = xl[gidx]; ly = yl[gidx]; lz = zl[gidx]; \
    if (t==0){ nx[i]=lx; ny[i]=ly; nz[i]=lz; }

#define FPS1_BLOCK_SETUP() \
  const int b = blockIdx.x; \
  const int wave = t >> 6; \
  const float* xs = g_ws + OFF_XS + (size_t)b*NN; \
  const float* ys = g_ws + OFF_YS + (size_t)b*NN; \
  const float* zs = g_ws + OFF_ZS + (size_t)b*NN; \
  float* nx = g_ws + OFF_NX1X + (size_t)b*S1; \
  float* ny = g_ws + OFF_NX1Y + (size_t)b*S1; \
  float* nz = g_ws + OFF_NX1Z + (size_t)b*S1; \
  float* ddg = g_ws + OFF_X3 + (size_t)b*NN; \
  __shared__ float xl[NN], yl[NN], zl[NN]; \
  __shared__ float s_val[2][4]; __shared__ int s_idx[2][4]; \
  FPS_DECL(0) FPS_DECL(1) FPS_DECL(2) FPS_DECL(3) FPS_DECL(4) FPS_DECL(5) FPS_DECL(6) FPS_DECL(7)

// R28: pointer-based setup for union-smem kernels (same names FPS macros expect)
#define FPS1_BLOCK_SETUP_U(SM) \
  const int b = blockIdx.x; \
  const int wave = t >> 6; \
  const float* xs = g_ws + OFF_XS + (size_t)b*NN; \
  const float* ys = g_ws + OFF_YS + (size_t)b*NN; \
  const float* zs = g_ws + OFF_ZS + (size_t)b*NN; \
  float* nx = g_ws + OFF_NX1X + (size_t)b*S1; \
  float* ny = g_ws + OFF_NX1Y + (size_t)b*S1; \
  float* nz = g_ws + OFF_NX1Z + (size_t)b*S1; \
  float* ddg = g_ws + OFF_X3 + (size_t)b*NN; \
  float* xl = (float*)(SM); float* yl = xl + NN; float* zl = yl + NN; \
  float (*s_val)[4] = (float(*)[4])(zl + NN); \
  int (*s_idx)[4] = (int(*)[4])((char*)(zl + NN) + 32); \
  FPS_DECL(0) FPS_DECL(1) FPS_DECL(2) FPS_DECL(3) FPS_DECL(4) FPS_DECL(5) FPS_DECL(6) FPS_DECL(7)

// K1: fps1 iters [1,SP1) + cvt_bf16 (blocks 32..287)
__global__ __launch_bounds__(256,1) void fps1A_cvt_kernel(){
  const int t = threadIdx.x;
  if (blockIdx.x >= 32){
    cvt_bf16_body((blockIdx.x-32)*256 + t, 256*256);
    return;
  }
  FPS1_BLOCK_SETUP()
  FPS_LD256A(0) FPS_LD256A(1) FPS_LD256A(2) FPS_LD256A(3) FPS_LD256A(4) FPS_LD256A(5) FPS_LD256A(6) FPS_LD256A(7)
  __syncthreads();
  float lx = xl[0], ly = yl[0], lz = zl[0];
  if (t==0){ nx[0]=lx; ny[0]=ly; nz[0]=lz; }
  for (int i=1;i<SP1;i++){
    FPS1_ITER_BODY()
  }
  FPS_SAVE(0) FPS_SAVE(1) FPS_SAVE(2) FPS_SAVE(3) FPS_SAVE(4) FPS_SAVE(5) FPS_SAVE(6) FPS_SAVE(7)
}

// ---------------- KNN1 body (R20: direct-d tournament + DPP argmin) ----------------
#define KNN1_POISON(C) case C: d[C] = match ? 3.0e38f : d[C]; break;
DEVI void knn1_body(int wid, int lane){
  int b = wid >> 9;
  const float* xs = g_ws + OFF_XS + (size_t)b*NN;
  const float* ys = g_ws + OFF_YS + (size_t)b*NN;
  const float* zs = g_ws + OFF_ZS + (size_t)b*NN;
  const float* sq = g_ws + OFF_SSQ + (size_t)b*NN;
  float cx = g_ws[OFF_NX1X + wid], cy = g_ws[OFF_NX1Y + wid], cz = g_ws[OFF_NX1Z + wid];
  float sc = sq3(cx,cy,cz);
  float d[32];
  #pragma unroll
  for (int c=0;c<32;c++){
    int n = c*64 + lane;
    float x=xs[n], y=ys[n], z=zs[n];
    float dot = rn_add(rn_add(rn_mul(cx,x),rn_mul(cy,y)),rn_mul(cz,z));
    d[c] = rn_sub(rn_add(sc,sq[n]), rn_mul(2.f,dot));
  }
  int* out = (int*)(g_ws + OFF_KNN1) + (size_t)wid*16;
  for (int r=0;r<16;r++){
    float tv[16]; int tc[16];
    #pragma unroll
    for (int c=0;c<16;c++){
      float a = d[2*c];
      float e = d[2*c+1];
      bool cc = e < a;
      tv[c] = cc ? e : a; tc[c] = cc ? (2*c+1) : (2*c);
    }
    #pragma unroll
    for (int s=1; s<16; s<<=1){
      #pragma unroll
      for (int c=0;c<16;c+=2){
        if ((c % (2*s)) == 0 && c+s < 16){
          bool cc = tv[c+s] < tv[c];
          tv[c] = cc ? tv[c+s] : tv[c];
          tc[c] = cc ? tc[c+s] : tc[c];
        }
      }
    }
    float best = tv[0]; int bidx = tc[0]*64 + lane;   // bidx IS the point index
    WAVE_ARGMIN()                                     // lane 63 holds wave argmin
    int wbi = __builtin_amdgcn_readlane(bidx, 63);    // wave-uniform winner
    if (lane == 0) out[r] = wbi;
    bool match = (lane == (wbi & 63));
    switch ((wbi >> 6) & 31){
      KNN1_POISON(0)  KNN1_POISON(1)  KNN1_POISON(2)  KNN1_POISON(3)
      KNN1_POISON(4)  KNN1_POISON(5)  KNN1_POISON(6)  KNN1_POISON(7)
      KNN1_POISON(8)  KNN1_POISON(9)  KNN1_POISON(10) KNN1_POISON(11)
      KNN1_POISON(12) KNN1_POISON(13) KNN1_POISON(14) KNN1_POISON(15)
      KNN1_POISON(16) KNN1_POISON(17) KNN1_POISON(18) KNN1_POISON(19)
      KNN1_POISON(20) KNN1_POISON(21) KNN1_POISON(22) KNN1_POISON(23)
      KNN1_POISON(24) KNN1_POISON(25) KNN1_POISON(26) KNN1_POISON(27)
      KNN1_POISON(28) KNN1_POISON(29) KNN1_POISON(30) KNN1_POISON(31)
    }
  }
}

// ---------------- SA1 body (factored; bxx covers gids [16*bxx, 16*bxx+16)) ----------------
DEVI void sa1_body(int br, int bxx, float* w1s, float* b1s, short* Hh, short* Hl){
  const int t = threadIdx.x;
  const int wave = t>>6, lane = t&63, quad = lane>>4, l16 = lane&15;
  for (int i=t;i<384;i+=256) w1s[i] = g_ws[W1A + (size_t)br*384 + i];
  if (t<64) b1s[t] = g_ws[B1A + br*64 + t];
  __syncthreads();                                  // cross-wave (w1s/b1s) — keep
  const int* kn = (const int*)(g_ws + OFF_KNN1);
  const short* w2h = (const short*)(g_ws + OFF_W2ABH) + (size_t)br*128*64;
  const short* w2l = (const short*)(g_ws + OFF_W2ABL) + (size_t)br*128*64;
  const float* b2 = g_ws + B2A + br*128;
  for (int it=0; it<4; it++){
    int gid = bxx*16 + it*4 + wave;
    int b = gid >> 9;
    int idx = kn[(size_t)gid*16 + l16] & (NN-1);
    float cx = g_ws[OFF_NX1X+gid], cy = g_ws[OFF_NX1Y+gid], cz = g_ws[OFF_NX1Z+gid];
    size_t gl = (size_t)b*NN + idx;
    float x = g_ws[OFF_XS+gl], y = g_ws[OFF_YS+gl], z = g_ws[OFF_ZS+gl];
    float f0=x-cx, f1=y-cy, f2=z-cz;
    #pragma unroll
    for (int i=0;i<16;i++){
      int h = quad*16 + i;
      float acc = b1s[h];
      acc += f0*w1s[h*6+0] + f1*w1s[h*6+1] + f2*w1s[h*6+2]
           +  x*w1s[h*6+3] +  y*w1s[h*6+4] +  z*w1s[h*6+5];
      acc = fmaxf(acc, 0.f);
      unsigned short hi = f2bf(acc);
      Hh[wave*1152 + l16*72 + h] = (short)hi;
      Hl[wave*1152 + l16*72 + h] = (short)f2bf(acc - bfbits2f(hi));
    }
    // (no __syncthreads: Hh/Hl exchange is wave-local; lgkmcnt orders it)
    s16x8 ah[2], al[2];
    #pragma unroll
    for (int ks=0;ks<2;ks++){
      ah[ks] = *(const s16x8*)(&Hh[wave*1152 + l16*72 + ks*32 + quad*8]);
      al[ks] = *(const s16x8*)(&Hl[wave*1152 + l16*72 + ks*32 + quad*8]);
    }
    unsigned short* P1g = (unsigned short*)(g_ws + OFF_P1) + ((size_t)br*16384 + gid)*128;
    #pragma unroll
    for (int ni=0; ni<8; ni++){
      int o = ni*16 + l16;
      f32x4 acc = {0.f,0.f,0.f,0.f};
      #pragma unroll
      for (int ks=0; ks<2; ks++){
        s16x8 bh = *(const s16x8*)(w2h + (size_t)o*64 + ks*32 + quad*8);
        s16x8 bl = *(const s16x8*)(w2l + (size_t)o*64 + ks*32 + quad*8);
        mfma16(acc, ah[ks], bh);
        mfma16(acc, ah[ks], bl);
        mfma16(acc, al[ks], bh);
      }
      mfma_guard(acc);
      float vmax = fmaxf(fmaxf(acc[0],acc[1]), fmaxf(acc[2],acc[3]));
      vmax = fmaxf(vmax, __shfl_xor(vmax,16));
      vmax = fmaxf(vmax, __shfl_xor(vmax,32));
      if (quad==0) P1g[o] = f2bf(vmax + b2[o]);     // R24: bf16
    }
  }
}

// K2: fps1 iters [SP1,SP2) (blocks 0..31) + knn1 centers [0,160) (blocks 32..1311)
__global__ __launch_bounds__(256,1) void fps1B_knn1a_kernel(){
  const int t = threadIdx.x;
  if (blockIdx.x >= 32){
    int lin = ((blockIdx.x-32)*256 + t) >> 6;   // [0, 5120)
    int b = lin / 160, s = lin % 160;
    knn1_body(b*S1 + s, t & 63);
    return;
  }
  FPS1_BLOCK_SETUP()
  FPS_LD256B(0) FPS_LD256B(1) FPS_LD256B(2) FPS_LD256B(3) FPS_LD256B(4) FPS_LD256B(5) FPS_LD256B(6) FPS_LD256B(7)
  __syncthreads();
  float lx = nx[SP1-1], ly = ny[SP1-1], lz = nz[SP1-1];  // bits identical to segA's final state
  for (int i=SP1;i<SP2;i++){
    FPS1_ITER_BODY()
  }
  FPS_SAVE(0) FPS_SAVE(1) FPS_SAVE(2) FPS_SAVE(3) FPS_SAVE(4) FPS_SAVE(5) FPS_SAVE(6) FPS_SAVE(7)
}

// K3 (R28): fps1 iters [SP2,512) (0..31) + knn1 [160,336) (32..1439) + sa1 sblk 0..9 (1440..2399)
// Union smem: fps role uses 24.6KB xl/yl/zl+combine; sa1 role uses 20.2KB
// w1s/b1s/Hh/Hl. Aliasing one buffer keeps LDS_Block_Size ~24.6KB -> 6 blk/CU.
__global__ __launch_bounds__(256,1) void fps1C_knn1b_sa1a_kernel(){
  __shared__ __align__(16) char smem[3*NN*4 + 64];
  const int t = threadIdx.x;
  if (blockIdx.x >= 1440){
    int q = blockIdx.x - 1440;           // [0, 960) = 3 br x 32 b x 10 sblk
    int br = q / 320, rem = q % 320;
    int b = rem / 10, sblk = rem % 10;   // centers s <= 159 < 160 (knn1a done end-K2)
    float* w1s = (float*)smem;
    float* b1s = w1s + 384;
    short* Hh = (short*)(b1s + 64);
    short* Hl = Hh + 4608;
    sa1_body(br, b*32 + sblk, w1s, b1s, Hh, Hl);
    return;
  }
  if (blockIdx.x >= 32){
    int lin = ((blockIdx.x-32)*256 + t) >> 6;   // [0, 5632)
    int b = lin / 176, s = 160 + lin % 176;
    knn1_body(b*S1 + s, t & 63);
    return;
  }
  FPS1_BLOCK_SETUP_U(smem)
  FPS_LD256B(0) FPS_LD256B(1) FPS_LD256B(2) FPS_LD256B(3) FPS_LD256B(4) FPS_LD256B(5) FPS_LD256B(6) FPS_LD256B(7)
  __syncthreads();
  float lx = nx[SP2-1], ly = ny[SP2-1], lz = nz[SP2-1];  // bits identical to segB's final state
  for (int i=SP2;i<S1;i++){
    FPS1_ITER_BODY()
  }
}

// K4: fps2 (0..31) + knn1 centers [336,512) (32..1439) + sa1 sblk 10..20 (1440..2495)
__global__ __launch_bounds__(256) void fps2_knn1c_sa1a_kernel(){
  __shared__ float xl[S1], yl[S1], zl[S1];
  __shared__ float w1s[384];
  __shared__ float b1s[64];
  __shared__ __align__(16) short Hh[4*16*72];
  __shared__ __align__(16) short Hl[4*16*72];
  const int t = threadIdx.x;
  if (blockIdx.x >= 1440){
    int q = blockIdx.x - 1440;           // [0, 1056) = 3 br x 32 b x 11 sblk
    int br = q / 352, rem = q % 352;
    int b = rem / 11, sblk = 10 + rem % 11;  // centers s in [160,336) (knn1b done end-K3)
    sa1_body(br, b*32 + sblk, w1s, b1s, Hh, Hl);
    return;
  }
  if (blockIdx.x >= 32){
    int lin = ((blockIdx.x-32)*256 + t) >> 6;   // [0, 5632)
    int b = lin / 176, s = 336 + lin % 176;
    knn1_body(b*S1 + s, t & 63);
    return;
  }
  if (t >= 64) return;
  const int b = blockIdx.x;
  const float* xs = g_ws + OFF_NX1X + (size_t)b*S1;
  const float* ys = g_ws + OFF_NX1Y + (size_t)b*S1;
  const float* zs = g_ws + OFF_NX1Z + (size_t)b*S1;
  float* nx = g_ws + OFF_NX2X + (size_t)b*S2;
  float* ny = g_ws + OFF_NX2Y + (size_t)b*S2;
  float* nz = g_ws + OFF_NX2Z + (size_t)b*S2;
  FPS_DECL(0) FPS_DECL(1) FPS_DECL(2) FPS_DECL(3) FPS_DECL(4) FPS_DECL(5) FPS_DECL(6) FPS_DECL(7)
  FPS_LD64(0) FPS_LD64(1) FPS_LD64(2) FPS_LD64(3) FPS_LD64(4) FPS_LD64(5) FPS_LD64(6) FPS_LD64(7)
  float lx = xl[0], ly = yl[0], lz = zl[0];
  if (t==0){ nx[0]=lx; ny[0]=ly; nz[0]=lz; }
  for (int i=1;i<S2;i++){
    FPS_UPD(0) FPS_UPD(1) FPS_UPD(2) FPS_UPD(3) FPS_UPD(4) FPS_UPD(5) FPS_UPD(6) FPS_UPD(7)
    FPS_T1(0,0,1) FPS_T1(1,2,3) FPS_T1(2,4,5) FPS_T1(3,6,7)
    FPS_T2(0,1) FPS_T2(2,3)
    FPS_T2(0,2)
    float best = v0; int bidx = q0*64 + t;
    WAVE_ARGMAX()
    int gidx = __builtin_amdgcn_readlane(bidx, 63);
    lx = xl[gidx]; ly = yl[gidx]; lz = zl[gidx];
    if (t==0){ nx[i]=lx; ny[i]=ly; nz[i]=lz; }
  }
}

// ---------------- KNN2 body (R20: direct-d tournament + DPP argmin) ----------------
#define KNN2_POISON(C) case C: d[C] = match ? 3.0e38f : d[C]; break;
DEVI void knn2_body(int wid, int lane){
  int b = wid >> 7;
  const float* xs = g_ws + OFF_NX1X + (size_t)b*S1;
  const float* ys = g_ws + OFF_NX1Y + (size_t)b*S1;
  const float* zs = g_ws + OFF_NX1Z + (size_t)b*S1;
  float cx = g_ws[OFF_NX2X + wid], cy = g_ws[OFF_NX2Y + wid], cz = g_ws[OFF_NX2Z + wid];
  float sc = sq3(cx,cy,cz);
  float d[8];
  #pragma unroll
  for (int c=0;c<8;c++){
    int n = c*64 + lane;
    float x=xs[n], y=ys[n], z=zs[n];
    float sx = sq3(x,y,z);
    float dot = rn_add(rn_add(rn_mul(cx,x),rn_mul(cy,y)),rn_mul(cz,z));
    d[c] = rn_sub(rn_add(sc,sx), rn_mul(2.f,dot));
  }
  int* out = (int*)(g_ws + OFF_KNN2) + (size_t)wid*48;
  for (int r=0;r<48;r++){
    float tv[4]; int tc[4];
    #pragma unroll
    for (int c=0;c<4;c++){
      float a = d[2*c];
      float e = d[2*c+1];
      bool cc = e < a;
      tv[c] = cc ? e : a; tc[c] = cc ? (2*c+1) : (2*c);
    }
    { bool cc = tv[1] < tv[0]; tv[0] = cc?tv[1]:tv[0]; tc[0] = cc?tc[1]:tc[0]; }
    { bool cc = tv[3] < tv[2]; tv[2] = cc?tv[3]:tv[2]; tc[2] = cc?tc[3]:tc[2]; }
    { bool cc = tv[2] < tv[0]; tv[0] = cc?tv[2]:tv[0]; tc[0] = cc?tc[2]:tc[0]; }
    float best = tv[0]; int bidx = tc[0]*64 + lane;   // point index in [0,512)
    WAVE_ARGMIN()
    int wbi = __builtin_amdgcn_readlane(bidx, 63);
    if (lane == 0) out[r] = wbi;
    bool match = (lane == (wbi & 63));
    switch ((wbi >> 6) & 7){
      KNN2_POISON(0) KNN2_POISON(1) KNN2_POISON(2) KNN2_POISON(3)
      KNN2_POISON(4) KNN2_POISON(5) KNN2_POISON(6) KNN2_POISON(7)
    }
  }
}

// K5: knn2 (blocks 0..1023) + sa1 sblk 21..31 (blocks 1024..2079)
__global__ __launch_bounds__(256) void knn2_sa1b_kernel(){
  __shared__ float w1s[384];
  __shared__ float b1s[64];
  __shared__ __align__(16) short Hh[4*16*72];
  __shared__ __align__(16) short Hl[4*16*72];
  const int t = threadIdx.x;
  if (blockIdx.x < 1024){
    knn2_body((blockIdx.x*256 + t) >> 6, t & 63);
    return;
  }
  int q = blockIdx.x - 1024;              // [0, 1056) = 3 br x 32 b x 11 sblk
  int br = q / 352, rem = q % 352;
  int b = rem / 11, sblk = 21 + rem % 11;
  sa1_body(br, b*32 + sblk, w1s, b1s, Hh, Hl);
}

// ---------------- SA2 (all branches) -> X3 bf16 hi/lo ----------------
// R30: (a) Hb row stride 136 -> 140 shorts (68 -> 70 words; quad rows land on
// banks {0,24,16,8} instead of {0,16,0,16} -> kills the 4-way write conflict).
// (b) staging loads batched into registers (K/8 independent loads in flight).
// (c) layer1 preloads both ni weight fragments and shares the Xb A-fragment;
// layer2 runs two 2-ni passes sharing the Hb A-fragment. All MFMA chains,
// bias adds, and fmax orders are unchanged -> bit-exact.
static constexpr int HBS = 140;

template<int K>
DEVI void sa2_body(int br, int g2, short* Xb, short* Hb, float* ctr, int* idxs){
  constexpr int MT = K/16;
  const int b = g2 >> 7;
  const int t = threadIdx.x;
  const int wave = t >> 6, lane = t & 63, quad = lane >> 4, l16 = lane & 15;
  const int* kn2 = (const int*)(g_ws + OFF_KNN2) + (size_t)g2*48;
  if (t < K) idxs[t] = kn2[t] & (S1-1);
  if (t < 3) ctr[t] = g_ws[(t==0?OFF_NX2X:(t==1?OFF_NX2Y:OFF_NX2Z)) + g2];
  __syncthreads();
  const unsigned short* p1b = (const unsigned short*)(g_ws + OFF_P1) + (size_t)br*16384*128;
  const int grp = t >> 5, gl = t & 31;
  unsigned long long wv[K/8];
  #pragma unroll
  for (int i=0;i<K/8;i++){
    int k = grp + i*8;
    const unsigned short* row = p1b + ((size_t)b*S1 + idxs[k])*128;
    wv[i] = *(const unsigned long long*)(row + gl*4);   // 4 bf16, 8B aligned
  }
  #pragma unroll
  for (int i=0;i<K/8;i++){
    int k = grp + i*8;
    short* dst = &Xb[k*168 + 3 + gl*4];
    dst[0] = (short)(wv[i] & 0xFFFF);
    dst[1] = (short)((wv[i] >> 16) & 0xFFFF);
    dst[2] = (short)((wv[i] >> 32) & 0xFFFF);
    dst[3] = (short)((wv[i] >> 48) & 0xFFFF);
    Xb[k*168 + 131 + gl] = 0;
    if (gl < 5)  Xb[k*168 + 163 + gl] = 0;
  }
  if (t < K){
    int idx = idxs[t];
    float c0 = g_ws[OFF_NX1X + (size_t)b*S1 + idx] - ctr[0];
    float c1 = g_ws[OFF_NX1Y + (size_t)b*S1 + idx] - ctr[1];
    float c2 = g_ws[OFF_NX1Z + (size_t)b*S1 + idx] - ctr[2];
    Xb[t*168+0] = (short)f2bf(c0);
    Xb[t*168+1] = (short)f2bf(c1);
    Xb[t*168+2] = (short)f2bf(c2);
  }
  __syncthreads();
  {
    const short* w1bf = (const short*)(g_ws + OFF_W1BF) + (size_t)br*128*160;
    const float* b1 = g_ws + B1B + br*128;
    const int h0 = wave*16 + l16, h1 = h0 + 64;      // ni = wave, wave+4
    s16x8 bA[5], bB[5];
    #pragma unroll
    for (int ks=0;ks<5;ks++){
      bA[ks] = *(const s16x8*)(w1bf + (size_t)h0*160 + ks*32 + quad*8);
      bB[ks] = *(const s16x8*)(w1bf + (size_t)h1*160 + ks*32 + quad*8);
    }
    const float biasA = b1[h0], biasB = b1[h1];
    #pragma unroll
    for (int m=0; m<MT; m++){
      f32x4 accA = {0.f,0.f,0.f,0.f}, accB = {0.f,0.f,0.f,0.f};
      #pragma unroll
      for (int ks=0;ks<5;ks++){
        s16x8 a = *(const s16x8*)(&Xb[(m*16 + l16)*168 + ks*32 + quad*8]);
        mfma16(accA, a, bA[ks]);
        mfma16(accB, a, bB[ks]);
      }
      mfma_guard(accA); mfma_guard(accB);
      #pragma unroll
      for (int r=0;r<4;r++){
        int row = m*16 + quad*4 + r;
        Hb[row*HBS + h0] = (short)f2bf(fmaxf(accA[r] + biasA, 0.f));
        Hb[row*HBS + h1] = (short)f2bf(fmaxf(accB[r] + biasB, 0.f));
      }
    }
  }
  __syncthreads();
  {
    const short* w2bf = (const short*)(g_ws + OFF_W2BF) + (size_t)br*256*128;
    const float* b2 = g_ws + B2B + br*256;
    unsigned short* xh = (unsigned short*)(g_ws + OFF_X3BH);
    unsigned short* xlo = (unsigned short*)(g_ws + OFF_X3BL);
    size_t row = (size_t)(br*4096 + g2)*288;
    #pragma unroll
    for (int p=0;p<2;p++){
      const int o0 = (wave + 8*p)*16 + l16, o1 = o0 + 64;   // ni = wave+8p, wave+8p+4
      s16x8 c0[4], c1[4];
      #pragma unroll
      for (int ks=0;ks<4;ks++){
        c0[ks] = *(const s16x8*)(w2bf + (size_t)o0*128 + ks*32 + quad*8);
        c1[ks] = *(const s16x8*)(w2bf + (size_t)o1*128 + ks*32 + quad*8);
      }
      float v0 = -3.4e38f, v1 = -3.4e38f;
      #pragma unroll
      for (int m=0; m<MT; m++){
        f32x4 a0 = {0.f,0.f,0.f,0.f}, a1 = {0.f,0.f,0.f,0.f};
        #pragma unroll
        for (int ks=0;ks<4;ks++){
          s16x8 a = *(const s16x8*)(&Hb[(m*16 + l16)*HBS + ks*32 + quad*8]);
          mfma16(a0, a, c0[ks]);
          mfma16(a1, a, c1[ks]);
        }
        mfma_guard(a0); mfma_guard(a1);
        #pragma unroll
        for (int r=0;r<4;r++){ v0 = fmaxf(v0, a0[r]); v1 = fmaxf(v1, a1[r]); }
      }
      v0 = fmaxf(v0, __shfl_xor(v0, 16));
      v0 = fmaxf(v0, __shfl_xor(v0, 32));
      v1 = fmaxf(v1, __shfl_xor(v1, 16));
      v1 = fmaxf(v1, __shfl_xor(v1, 32));
      if (quad == 0){
        float hv = v0 + b2[o0];
        unsigned short hi = f2bf(hv);
        xh[row + 3 + o0] = hi;
        xlo[row + 3 + o0] = f2bf(hv - bfbits2f(hi));
        hv = v1 + b2[o1];
        hi = f2bf(hv);
        xh[row + 3 + o1] = hi;
        xlo[row + 3 + o1] = f2bf(hv - bfbits2f(hi));
      }
    }
    if (t < 3){
      float cv = ctr[t];
      unsigned short hi = f2bf(cv);
      xh[row + t] = hi; xlo[row + t] = f2bf(cv - bfbits2f(hi));
    }
    if (t >= 3 && t < 32){ xh[row + 256 + t] = 0; xlo[row + 256 + t] = 0; }
  }
}

// R29: XCD-chunked work remap. blockIdx%8 ~ XCD on MI355X (8 XCDs, round-robin
// dispatch). Each XCD owns 4 complete batches x 3 branches x 128 centers so its
// P1 gather working set (1.57 MB) fits the 4MB per-XCD L2 (FETCH 40->8MB, R29).
__global__ __launch_bounds__(256) void sa2_all_kernel(){
  __shared__ __align__(16) short Xb[48*168];
  __shared__ __align__(16) short Hb[48*HBS];
  __shared__ float ctr[3];
  __shared__ int idxs[48];
  int xcd = blockIdx.x & 7;
  int idx = blockIdx.x >> 3;            // [0, 1536)
  int bloc = idx / 384;                 // 0..3
  int rem  = idx % 384;
  int br   = rem / 128;                 // 0..2
  int g2o  = rem % 128;
  int b    = xcd*4 + bloc;              // 0..31
  int g2   = b*128 + g2o;
  if (br == 0)      sa2_body<16>(0, g2, Xb, Hb, ctr, idxs);
  else if (br == 1) sa2_body<32>(1, g2, Xb, Hb, ctr, idxs);
  else              sa2_body<48>(2, g2, Xb, Hb, ctr, idxs);
}

// ---------------- SA3 layer1 via MFMA (hi/lo): 288 -> 512 relu ----------------
__global__ __launch_bounds__(256) void sa3l1_mfma_kernel(){
  const int br = blockIdx.y; const int r0 = blockIdx.x*32;
  const int t = threadIdx.x;
  const int wave = t >> 6, lane = t & 63, quad = lane >> 4, l16 = lane & 15;
  const short* xh = (const short*)(g_ws + OFF_X3BH) + (size_t)(br*4096 + r0)*288;
  const short* xl = (const short*)(g_ws + OFF_X3BL) + (size_t)(br*4096 + r0)*288;
  const short* wh = (const short*)(g_ws + OFF_W1CBH) + (size_t)br*512*288;
  const short* wl = (const short*)(g_ws + OFF_W1CBL) + (size_t)br*512*288;
  const float* bias = g_ws + B1C + br*512;
  unsigned short* hh = (unsigned short*)(g_ws + OFF_H3BH) + (size_t)(br*4096 + r0)*512;
  unsigned short* hl = (unsigned short*)(g_ws + OFF_H3BL) + (size_t)(br*4096 + r0)*512;
  f32x4 acc[2][8];
  #pragma unroll
  for (int m=0;m<2;m++)
    #pragma unroll
    for (int ni=0;ni<8;ni++) acc[m][ni] = (f32x4){0.f,0.f,0.f,0.f};
  for (int ks=0; ks<9; ks++){
    s16x8 ah[2], al[2];
    #pragma unroll
    for (int m=0;m<2;m++){
      ah[m] = *(const s16x8*)(xh + (size_t)(m*16+l16)*288 + ks*32 + quad*8);
      al[m] = *(const s16x8*)(xl + (size_t)(m*16+l16)*288 + ks*32 + quad*8);
    }
    #pragma unroll
    for (int ni=0;ni<8;ni++){
      int n = wave*128 + ni*16 + l16;
      s16x8 bh = *(const s16x8*)(wh + (size_t)n*288 + ks*32 + quad*8);
      s16x8 bl = *(const s16x8*)(wl + (size_t)n*288 + ks*32 + quad*8);
      #pragma unroll
      for (int m=0;m<2;m++){
        mfma16(acc[m][ni], ah[m], bh);
        mfma16(acc[m][ni], ah[m], bl);
        mfma16(acc[m][ni], al[m], bh);
      }
    }
  }
  mfma_guard(acc[0][0]);
  #pragma unroll
  for (int m=0;m<2;m++){
    #pragma unroll
    for (int ni=0;ni<8;ni++){
      int col = wave*128 + ni*16 + l16;
      float bs = bias[col];
      #pragma unroll
      for (int r=0;r<4;r++){
        int row = m*16 + quad*4 + r;
        float hv = fmaxf(acc[m][ni][r] + bs, 0.f);
        unsigned short hi = f2bf(hv);
        hh[(size_t)row*512 + col] = hi;
        hl[(size_t)row*512 + col] = f2bf(hv - bfbits2f(hi));
      }
    }
  }
}

// ---------------- SA3 layer2 via MFMA (hi/lo): 512 -> 512, partial max ----------------
__global__ __launch_bounds__(256) void sa3l2_mfma_kernel(){
  const int br = blockIdx.y; const int b = blockIdx.x>>2; const int part = blockIdx.x&3;
  const int t = threadIdx.x;
  const int wave = t >> 6, lane = t & 63, quad = lane >> 4, l16 = lane & 15;
  const int row0 = b*128 + part*32;
  const short* ahp = (const short*)(g_ws + OFF_H3BH) + (size_t)(br*4096 + row0)*512;
  const short* alp = (const short*)(g_ws + OFF_H3BL) + (size_t)(br*4096 + row0)*512;
  const short* wh = (const short*)(g_ws + OFF_W2CBH) + (size_t)br*512*512;
  const short* wl = (const short*)(g_ws + OFF_W2CBL) + (size_t)br*512*512;
  f32x4 acc[2][8];
  #pragma unroll
  for (int m=0;m<2;m++)
    #pragma unroll
    for (int ni=0;ni<8;ni++) acc[m][ni] = (f32x4){0.f,0.f,0.f,0.f};
  for (int ks=0; ks<16; ks++){
    s16x8 ah[2], al[2];
    #pragma unroll
    for (int m=0;m<2;m++){
      ah[m] = *(const s16x8*)(ahp + (size_t)(m*16+l16)*512 + ks*32 + quad*8);
      al[m] = *(const s16x8*)(alp + (size_t)(m*16+l16)*512 + ks*32 + quad*8);
    }
    #pragma unroll
    for (int ni=0;ni<8;ni++){
      int n = wave*128 + ni*16 + l16;
      s16x8 bh = *(const s16x8*)(wh + (size_t)n*512 + ks*32 + quad*8);
      s16x8 bl = *(const s16x8*)(wl + (size_t)n*512 + ks*32 + quad*8);
      #pragma unroll
      for (int m=0;m<2;m++){
        mfma16(acc[m][ni], ah[m], bh);
        mfma16(acc[m][ni], ah[m], bl);
        mfma16(acc[m][ni], al[m], bh);
      }
    }
  }
  mfma_guard(acc[0][0]);
  #pragma unroll
  for (int ni=0;ni<8;ni++){
    float vmax = -3.4e38f;
    #pragma unroll
    for (int m=0;m<2;m++)
      #pragma unroll
      for (int r=0;r<4;r++) vmax = fmaxf(vmax, acc[m][ni][r]);
    vmax = fmaxf(vmax, __shfl_xor(vmax, 16));
    vmax = fmaxf(vmax, __shfl_xor(vmax, 32));
    if (quad == 0){
      int col = wave*128 + ni*16 + l16;
      g_ws[OFF_O3P + (((size_t)br*BB + b)*4 + part)*512 + col] = vmax;
    }
  }
}

// ---------------- FC head + combine fused (f32 out) ----------------
__global__ __launch_bounds__(256) void fc_kernel(float* __restrict__ out, int out_size){
  int br = blockIdx.x >> 5; int b = blockIdx.x & 31; int t = threadIdx.x;
  __shared__ float xin[512]; __shared__ float x1s[256];
  const float* o3p = g_ws + OFF_O3P + (((size_t)br*BB + b)*4)*512;
  const float* b2c = g_ws + B2C + br*512;
  #pragma unroll
  for (int k=0;k<2;k++){
    int o = t + k*256;
    float m = fmaxf(fmaxf(o3p[o], o3p[512+o]), fmaxf(o3p[1024+o], o3p[1536+o]));
    m += b2c[o];
    xin[o] = m;
    int oi = 3*BB*128 + ((br*BB + b)*512) + o;
    if (oi < out_size) out[oi] = m;
  }
  __syncthreads();
  const float s = (float)(1.0 / sqrt(1.0 + 1e-5));
  {
    const float4* wp = (const float4*)(g_ws + FW1 + ((size_t)br*256 + t)*512);
    const float4* xp = (const float4*)xin;
    float acc = 0.f;
    #pragma unroll 8
    for (int q=0;q<128;q++){ float4 w4=wp[q], x4=xp[q]; acc += w4.x*x4.x + w4.y*x4.y + w4.z*x4.z + w4.w*x4.w; }
    acc = (acc + g_ws[FB1 + br*256+t]) * s;
    acc = g_ws[FG1+br*256+t]*acc + g_ws[FBE1+br*256+t];
    x1s[t] = fmaxf(acc, 0.f);
  }
  __syncthreads();
  if (t < 128){
    const float4* wp = (const float4*)(g_ws + FW2 + ((size_t)br*128 + t)*256);
    const float4* xp = (const float4*)x1s;
    float acc=0.f;
    #pragma unroll 8
    for (int q=0;q<64;q++){ float4 w4=wp[q], x4=xp[q]; acc += w4.x*x4.x + w4.y*x4.y + w4.z*x4.z + w4.w*x4.w; }
    acc = (acc + g_ws[FB2+br*128+t])*s;
    acc = g_ws[FG2+br*128+t]*acc + g_ws[FBE2+br*128+t];
    int oi = ((size_t)br*BB + b)*128 + t;
    if (oi < out_size) out[oi] = fmaxf(acc,0.f);
  }
}

// ---------------- launch (R30: sa2 ILP batch-loads + Hb stride 140) ----------------
extern "C" void kernel_launch(void* const* d_in, const int* in_sizes, int n_in,
                              void* d_out, int out_size, void* d_ws, size_t ws_size,
                              hipStream_t stream) {
  (void)d_ws; (void)ws_size;
  if (n_in < 21) return;
  if (in_sizes[0] != BB*3*NN) return;
  float* out = (float*)d_out;

  ParamPtrs pp;
  for (int i=0;i<20;i++) pp.p[i] = d_in[i+1];

  init_detect_kernel<<<1,256,0,stream>>>(d_in[0]);
  cvtprep_kernel<<<768,256,0,stream>>>(pp, d_in[0], 0);
  scan_check_kernel<<<256,256,0,stream>>>();
  resolve_flip_kernel<<<1,64,0,stream>>>();
  cvtprep_kernel<<<768,256,0,stream>>>(pp, d_in[0], 1);   // gated on g_flip

  fps1A_cvt_kernel<<<32+256,256,0,stream>>>();            // fps1 [1,171) + cvt_bf16
  fps1B_knn1a_kernel<<<32+1280,256,0,stream>>>();         // fps1 [171,342) || knn1 [0,160)
  fps1C_knn1b_sa1a_kernel<<<32+1408+960,256,0,stream>>>();// fps1 [342,512) || knn1 [160,336) || sa1 sblk 0..9
  fps2_knn1c_sa1a_kernel<<<32+1408+1056,256,0,stream>>>();// fps2 || knn1 [336,512) || sa1 sblk 10..20
  knn2_sa1b_kernel<<<1024+1056,256,0,stream>>>();         // knn2 || sa1 sblk 21..31
  sa2_all_kernel<<<3*4096,256,0,stream>>>();              // XCD-chunked (R29) + ILP/conflict fix (R30)

  sa3l1_mfma_kernel<<<dim3(128,3),256,0,stream>>>();
  sa3l2_mfma_kernel<<<dim3(128,3),256,0,stream>>>();
  fc_kernel<<<96,256,0,stream>>>(out, out_size);          // combine fused in
}

// Round 21
// 1013.104 us; speedup vs baseline: 1.0390x; 1.0390x over previous
//
#include <hip/hip_runtime.h>
#include <hip/hip_bf16.h>
#include <math.h>

#define DEVI __device__ __forceinline__

static constexpr int BB = 32, NN = 2048, S1 = 512, S2 = 128;

typedef float f32x4 __attribute__((ext_vector_type(4)));
typedef short s16x8 __attribute__((ext_vector_type(8)));

// ---------------- static workspace layout (float units) ----------------
static constexpr size_t OFF_XS   = 0;
static constexpr size_t OFF_YS   = OFF_XS + (size_t)BB*NN;
static constexpr size_t OFF_ZS   = OFF_YS + (size_t)BB*NN;
static constexpr size_t OFF_SSQ  = OFF_ZS + (size_t)BB*NN;
static constexpr size_t OFF_NX1X = OFF_SSQ + (size_t)BB*NN;
static constexpr size_t OFF_NX1Y = OFF_NX1X + (size_t)BB*S1;
static constexpr size_t OFF_NX1Z = OFF_NX1Y + (size_t)BB*S1;
static constexpr size_t OFF_NX2X = OFF_NX1Z + (size_t)BB*S1;
static constexpr size_t OFF_NX2Y = OFF_NX2X + (size_t)BB*S2;
static constexpr size_t OFF_NX2Z = OFF_NX2Y + (size_t)BB*S2;
static constexpr size_t OFF_CODE = OFF_NX2Z + (size_t)BB*S2;          // (unused)
static constexpr size_t OFF_O3P  = OFF_CODE + (size_t)3*BB*512;
static constexpr size_t OFF_P1   = OFF_O3P + (size_t)3*BB*4*512;      // R24: bf16 (ushort), rows of 128
static constexpr size_t OFF_X3   = OFF_P1 + (size_t)3*BB*S1*128;      // reused: fps1 dd spill (BB*NN floats)
static constexpr size_t OFF_H3   = OFF_X3 + (size_t)3*BB*S2*260;     // (unused)
static constexpr size_t OFF_W    = OFF_H3 + (size_t)3*BB*S2*512;
static constexpr size_t W1A  = OFF_W;
static constexpr size_t B1A  = W1A + 3*64*6;
static constexpr size_t W2A  = B1A + 3*64;
static constexpr size_t B2A  = W2A + 3*128*64;
static constexpr size_t W1B  = B2A + 3*128;
static constexpr size_t B1B  = W1B + 3*128*132;
static constexpr size_t W2B  = B1B + 3*128;
static constexpr size_t B2B  = W2B + 3*256*128;
static constexpr size_t W1C  = B2B + 3*256;
static constexpr size_t B1C  = W1C + 3*512*260;
static constexpr size_t W2C  = B1C + 3*512;
static constexpr size_t B2C  = W2C + 3*512*512;
static constexpr size_t FW1  = B2C + 3*512;
static constexpr size_t FB1  = FW1 + 3*256*512;
static constexpr size_t FG1  = FB1 + 3*256;
static constexpr size_t FBE1 = FG1 + 3*256;
static constexpr size_t FW2  = FBE1 + 3*256;
static constexpr size_t FB2  = FW2 + 3*128*256;
static constexpr size_t FG2  = FB2 + 3*128;
static constexpr size_t FBE2 = FG2 + 3*128;
static constexpr size_t OFF_KNN1 = FBE2 + 3*128;
static constexpr size_t OFF_KNN2 = OFF_KNN1 + (size_t)BB*S1*16;
static constexpr size_t OFF_W1BF = OFF_KNN2 + (size_t)BB*S2*48;
static constexpr size_t OFF_W2BF = OFF_W1BF + 30720;
static constexpr size_t OFF_W1CBH = OFF_W2BF + 49152;
static constexpr size_t OFF_W1CBL = OFF_W1CBH + 221184;
static constexpr size_t OFF_W2CBH = OFF_W1CBL + 221184;
static constexpr size_t OFF_W2CBL = OFF_W2CBH + 393216;
static constexpr size_t OFF_X3BH  = OFF_W2CBL + 393216;
static constexpr size_t OFF_X3BL  = OFF_X3BH + 1769472;
static constexpr size_t OFF_H3BH  = OFF_X3BL + 1769472;
static constexpr size_t OFF_H3BL  = OFF_H3BH + 3145728;
static constexpr size_t OFF_W2ABH = OFF_H3BL + 3145728;
static constexpr size_t OFF_W2ABL = OFF_W2ABH + 12288;
static constexpr size_t WS_FLOATS = OFF_W2ABL + 12288;

__device__ __align__(16) float g_ws[WS_FLOATS];
__device__ int g_is_f32;
__device__ int g_flip;
__device__ int g_bad;
__device__ int g_nz;

DEVI float bf2f(const __hip_bfloat16 v){ return __bfloat162float(v); }
DEVI float rn_add(float a, float b){ return __fadd_rn(a,b); }
DEVI float rn_mul(float a, float b){ return __fmul_rn(a,b); }
DEVI float rn_sub(float a, float b){ return __fsub_rn(a,b); }
DEVI float sq3(float x,float y,float z){ return rn_add(rn_add(rn_mul(x,x),rn_mul(y,y)),rn_mul(z,z)); }

DEVI float ldany(const void* s, size_t i, int isf){
  return isf ? ((const float*)s)[i] : bf2f(((const __hip_bfloat16*)s)[i]);
}
DEVI unsigned short f2bf(float f){
  unsigned u = __float_as_uint(f);
  unsigned r = (u + 0x7FFFu + ((u>>16)&1u)) >> 16;
  return (unsigned short)r;
}
DEVI float bfbits2f(unsigned short h){ return __uint_as_float(((unsigned)h)<<16); }
DEVI void mfma16(f32x4& d, s16x8 a, s16x8 b){
  asm volatile("v_mfma_f32_16x16x32_bf16 %0, %1, %2, %0" : "+v"(d) : "v"(a), "v"(b));
}
DEVI void mfma_guard(f32x4& d){
  asm volatile("s_nop 7\n\ts_nop 7\n\ts_nop 2" : "+v"(d));
}

// DPP helpers (validated R12). old = self -> boundary lanes no-op.
#define DPPF(dst, src, CTRL) dst = __uint_as_float((unsigned)__builtin_amdgcn_update_dpp(\
    (int)__float_as_uint(src), (int)__float_as_uint(src), CTRL, 0xF, 0xF, false))
#define DPPI(dst, src, CTRL) dst = __builtin_amdgcn_update_dpp(src, src, CTRL, 0xF, 0xF, false)
#define RED_STEP(CTRL) { float ov; int oi; DPPF(ov, best, CTRL); DPPI(oi, bidx, CTRL); \
  if (ov > best || (ov == best && oi < bidx)){ best = ov; bidx = oi; } }
#define WAVE_ARGMAX() RED_STEP(0xB1) RED_STEP(0x4E) RED_STEP(0x124) RED_STEP(0x128) RED_STEP(0x142) RED_STEP(0x143)

// R20: DPP argmin (same validated ctrl sequence, predicate flipped). Result in lane 63.
#define REDMIN_STEP(CTRL) { float ov; int oi; DPPF(ov, best, CTRL); DPPI(oi, bidx, CTRL); \
  if (ov < best || (ov == best && oi < bidx)){ best = ov; bidx = oi; } }
#define WAVE_ARGMIN() REDMIN_STEP(0xB1) REDMIN_STEP(0x4E) REDMIN_STEP(0x124) REDMIN_STEP(0x128) REDMIN_STEP(0x142) REDMIN_STEP(0x143)

// ---------------- init + dtype detection ----------------
__global__ __launch_bounds__(256) void init_detect_kernel(const void* __restrict__ pc){
  __shared__ int s_cnt[256];
  int t = threadIdx.x;
  if (t==0){ g_flip=0; g_bad=0; g_nz=0; }
  const unsigned short* h = (const unsigned short*)pc;
  int weird = 0;
  for (int i=t; i<4096; i+=256){
    unsigned short v = h[2*i];
    int e = (v >> 7) & 0xFF;
    if (e == 0xFF || e < 90 || e > 140) weird++;
  }
  s_cnt[t] = weird; __syncthreads();
  for (int o=128;o>0;o>>=1){ if (t<o) s_cnt[t]+=s_cnt[t+o]; __syncthreads(); }
  if (t==0) g_is_f32 = (s_cnt[0] > 1024) ? 1 : 0;
}

// ---------------- fused param-convert + prep_xyz ----------------
struct ParamPtrs { const void* p[20]; };

DEVI void cvt_arr(const void* s, float* d, int n, int g, int gs, int isf){
  for (int i=g;i<n;i+=gs) d[i] = ldany(s,i,isf);
}
DEVI void cvt_pad(const void* s, float* d, int rows, int cin, int cinp, int g, int gs, int isf){
  int tot = rows*cinp;
  for (int i=g;i<tot;i+=gs){ int r=i/cinp, c=i%cinp; d[i] = (c<cin)? ldany(s,(size_t)r*cin+c,isf) : 0.f; }
}

// blocks 0-255: prep_xyz; blocks 256-767: cvt_params
__global__ __launch_bounds__(256) void cvtprep_kernel(ParamPtrs pp, const void* __restrict__ pc, int mode){
  if (mode==1 && g_flip==0) return;
  const int isf = g_is_f32 ^ mode;
  if (blockIdx.x < 256){
    int i = blockIdx.x*256 + threadIdx.x;
    int b = i >> 11, n = i & 2047;
    float x = ldany(pc, (size_t)(b*3+0)*2048 + n, isf);
    float y = ldany(pc, (size_t)(b*3+1)*2048 + n, isf);
    float z = ldany(pc, (size_t)(b*3+2)*2048 + n, isf);
    g_ws[OFF_XS+i]=x; g_ws[OFF_YS+i]=y; g_ws[OFF_ZS+i]=z;
    g_ws[OFF_SSQ+i]=sq3(x,y,z);
    return;
  }
  int g = (blockIdx.x-256)*256 + threadIdx.x; int gs = 512*256;
  float* ws = g_ws;
  cvt_arr(pp.p[0],  ws+W1A, 3*64*6, g, gs, isf);
  cvt_arr(pp.p[1],  ws+B1A, 3*64, g, gs, isf);
  cvt_arr(pp.p[2],  ws+W2A, 3*128*64, g, gs, isf);
  cvt_arr(pp.p[3],  ws+B2A, 3*128, g, gs, isf);
  cvt_pad(pp.p[4],  ws+W1B, 3*128, 131, 132, g, gs, isf);
  cvt_arr(pp.p[5],  ws+B1B, 3*128, g, gs, isf);
  cvt_arr(pp.p[6],  ws+W2B, 3*256*128, g, gs, isf);
  cvt_arr(pp.p[7],  ws+B2B, 3*256, g, gs, isf);
  cvt_pad(pp.p[8],  ws+W1C, 3*512, 259, 260, g, gs, isf);
  cvt_arr(pp.p[9],  ws+B1C, 3*512, g, gs, isf);
  cvt_arr(pp.p[10], ws+W2C, 3*512*512, g, gs, isf);
  cvt_arr(pp.p[11], ws+B2C, 3*512, g, gs, isf);
  cvt_arr(pp.p[12], ws+FW1, 3*256*512, g, gs, isf);
  cvt_arr(pp.p[13], ws+FB1, 3*256, g, gs, isf);
  cvt_arr(pp.p[14], ws+FG1, 3*256, g, gs, isf);
  cvt_arr(pp.p[15], ws+FBE1,3*256, g, gs, isf);
  cvt_arr(pp.p[16], ws+FW2, 3*128*256, g, gs, isf);
  cvt_arr(pp.p[17], ws+FB2, 3*128, g, gs, isf);
  cvt_arr(pp.p[18], ws+FG2, 3*128, g, gs, isf);
  cvt_arr(pp.p[19], ws+FBE2,3*128, g, gs, isf);
}

// ---------------- fused sanity scans (coords + FW1) ----------------
__global__ __launch_bounds__(256) void scan_check_kernel(){
  size_t off; int n, g, gs;
  if (blockIdx.x < 128){ off = OFF_XS; n = 3*BB*NN; g = blockIdx.x*256 + threadIdx.x; gs = 128*256; }
  else { off = FW1; n = 3*256*512; g = (blockIdx.x-128)*256 + threadIdx.x; gs = 128*256; }
  int bad=0, nz=0;
  for (int i=g;i<n;i+=gs){
    float v = g_ws[off + i];
    if (v != v || fabsf(v) > 1e4f) bad=1;
    if (fabsf(v) > 1e-20f) nz=1;
  }
  unsigned long long mb = __ballot(bad), mn = __ballot(nz);
  if ((threadIdx.x & 63)==0){
    if (mb) atomicOr(&g_bad, 1);
    if (mn) atomicOr(&g_nz, 1);
  }
}

__global__ __launch_bounds__(64) void resolve_flip_kernel(){
  if (threadIdx.x==0){
    g_flip = (g_bad || !g_nz) ? 1 : 0;
    g_bad = 0; g_nz = 0;
  }
}

// ---------------- bf16 weight conversion body ----------------
DEVI void cvt_bf16_body(int g, int gs){
  unsigned short* w1d = (unsigned short*)(g_ws + OFF_W1BF);
  for (int i=g; i<3*128*160; i+=gs){
    int br = i/(128*160); int rem = i%(128*160); int h = rem/160; int c = rem%160;
    float v = (c<132) ? g_ws[W1B + ((size_t)br*128 + h)*132 + c] : 0.f;
    w1d[i] = f2bf(v);
  }
  unsigned short* w2d = (unsigned short*)(g_ws + OFF_W2BF);
  for (int i=g; i<3*256*128; i+=gs) w2d[i] = f2bf(g_ws[W2B + i]);
  unsigned short* w1ch = (unsigned short*)(g_ws + OFF_W1CBH);
  unsigned short* w1cl = (unsigned short*)(g_ws + OFF_W1CBL);
  for (int i=g; i<3*512*288; i+=gs){
    int br = i/(512*288); int rem = i%(512*288); int n = rem/288; int c = rem%288;
    float v = (c<260) ? g_ws[W1C + ((size_t)br*512 + n)*260 + c] : 0.f;
    unsigned short hi = f2bf(v);
    w1ch[i] = hi; w1cl[i] = f2bf(v - bfbits2f(hi));
  }
  unsigned short* w2ch = (unsigned short*)(g_ws + OFF_W2CBH);
  unsigned short* w2cl = (unsigned short*)(g_ws + OFF_W2CBL);
  for (int i=g; i<3*512*512; i+=gs){
    float v = g_ws[W2C + i];
    unsigned short hi = f2bf(v);
    w2ch[i] = hi; w2cl[i] = f2bf(v - bfbits2f(hi));
  }
  unsigned short* w2ah = (unsigned short*)(g_ws + OFF_W2ABH);
  unsigned short* w2al = (unsigned short*)(g_ws + OFF_W2ABL);
  for (int i=g; i<3*128*64; i+=gs){
    float v = g_ws[W2A + i];
    unsigned short hi = f2bf(v);
    w2ah[i] = hi; w2al[i] = f2bf(v - bfbits2f(hi));
  }
}

// ---------------- FPS1 (R27: three-way split at iters 171/342, bit-exact dd carry) ----------------
static constexpr int SP1 = 171, SP2 = 342;

#define FPS_DECL(J) float px##J, py##J, pz##J, dd##J;
#define FPS_LD256A(J) { int n=(J)*256+t; px##J=xs[n]; py##J=ys[n]; pz##J=zs[n]; dd##J=1e10f; xl[n]=px##J; yl[n]=py##J; zl[n]=pz##J; }
#define FPS_LD256B(J) { int n=(J)*256+t; px##J=xs[n]; py##J=ys[n]; pz##J=zs[n]; dd##J=ddg[n]; xl[n]=px##J; yl[n]=py##J; zl[n]=pz##J; }
#define FPS_SAVE(J) ddg[(J)*256+t]=dd##J;
#define FPS_LD64(J) { int n=(J)*64+t; px##J=xs[n]; py##J=ys[n]; pz##J=zs[n]; dd##J=1e10f; xl[n]=px##J; yl[n]=py##J; zl[n]=pz##J; }
#define FPS_UPD(J) { float dx=rn_sub(px##J,lx), dy=rn_sub(py##J,ly), dz=rn_sub(pz##J,lz); float d=sq3(dx,dy,dz); dd##J=fminf(dd##J,d); }
#define FPS_T1(J,JA,JB) float v##J; int q##J; { bool c = dd##JB > dd##JA; v##J = c? dd##JB : dd##JA; q##J = c? (JB) : (JA); }
#define FPS_T2(JA,JB) { bool c = v##JB > v##JA; v##JA = c? v##JB : v##JA; q##JA = c? q##JB : q##JA; }

// R15-proven iteration body (4-wave parity combine + LDS gather), shared by all segments
#define FPS1_ITER_BODY() \
    FPS_UPD(0) FPS_UPD(1) FPS_UPD(2) FPS_UPD(3) FPS_UPD(4) FPS_UPD(5) FPS_UPD(6) FPS_UPD(7) \
    FPS_T1(0,0,1) FPS_T1(1,2,3) FPS_T1(2,4,5) FPS_T1(3,6,7) \
    FPS_T2(0,1) FPS_T2(2,3) \
    FPS_T2(0,2) \
    float best = v0; int bidx = q0*256 + t; \
    WAVE_ARGMAX() \
    int par = i & 1; \
    if ((t&63)==63){ s_val[par][wave]=best; s_idx[par][wave]=bidx; } \
    __syncthreads(); \
    float va = s_val[par][0], vb = s_val[par][1], vc = s_val[par][2], vd = s_val[par][3]; \
    int ia = s_idx[par][0], ib = s_idx[par][1], ic = s_idx[par][2], id_ = s_idx[par][3]; \
    if (vb > va || (vb == va && ib < ia)){ va = vb; ia = ib; } \
    if (vd > vc || (vd == vc && id_ < ic)){ vc = vd; ic = id_; } \
    if (vc > va || (vc == va && ic < ia)){ va = vc; ia = ic; } \
    int gidx = ia; \
    lx = xl[gidx]; ly = yl[gidx]; lz = zl[gidx]; \
    if (t==0){ nx[i]=lx; ny[i]=ly; nz[i]=lz; }

#define FPS1_BLOCK_SETUP() \
  const int b = blockIdx.x; \
  const int wave = t >> 6; \
  const float* xs = g_ws + OFF_XS + (size_t)b*NN; \
  const float* ys = g_ws + OFF_YS + (size_t)b*NN; \
  const float* zs = g_ws + OFF_ZS + (size_t)b*NN; \
  float* nx = g_ws + OFF_NX1X + (size_t)b*S1; \
  float* ny = g_ws + OFF_NX1Y + (size_t)b*S1; \
  float* nz = g_ws + OFF_NX1Z + (size_t)b*S1; \
  float* ddg = g_ws + OFF_X3 + (size_t)b*NN; \
  __shared__ float xl[NN], yl[NN], zl[NN]; \
  __shared__ float s_val[2][4]; __shared__ int s_idx[2][4]; \
  FPS_DECL(0) FPS_DECL(1) FPS_DECL(2) FPS_DECL(3) FPS_DECL(4) FPS_DECL(5) FPS_DECL(6) FPS_DECL(7)

// R28: pointer-based setup for union-smem kernels (same names FPS macros expect)
#define FPS1_BLOCK_SETUP_U(SM) \
  const int b = blockIdx.x; \
  const int wave = t >> 6; \
  const float* xs = g_ws + OFF_XS + (size_t)b*NN; \
  const float* ys = g_ws + OFF_YS + (size_t)b*NN; \
  const float* zs = g_ws + OFF_ZS + (size_t)b*NN; \
  float* nx = g_ws + OFF_NX1X + (size_t)b*S1; \
  float* ny = g_ws + OFF_NX1Y + (size_t)b*S1; \
  float* nz = g_ws + OFF_NX1Z + (size_t)b*S1; \
  float* ddg = g_ws + OFF_X3 + (size_t)b*NN; \
  float* xl = (float*)(SM); float* yl = xl + NN; float* zl = yl + NN; \
  float (*s_val)[4] = (float(*)[4])(zl + NN); \
  int (*s_idx)[4] = (int(*)[4])((char*)(zl + NN) + 32); \
  FPS_DECL(0) FPS_DECL(1) FPS_DECL(2) FPS_DECL(3) FPS_DECL(4) FPS_DECL(5) FPS_DECL(6) FPS_DECL(7)

// K1: fps1 iters [1,SP1) + cvt_bf16 (blocks 32..287)
__global__ __launch_bounds__(256,1) void fps1A_cvt_kernel(){
  const int t = threadIdx.x;
  if (blockIdx.x >= 32){
    cvt_bf16_body((blockIdx.x-32)*256 + t, 256*256);
    return;
  }
  FPS1_BLOCK_SETUP()
  FPS_LD256A(0) FPS_LD256A(1) FPS_LD256A(2) FPS_LD256A(3) FPS_LD256A(4) FPS_LD256A(5) FPS_LD256A(6) FPS_LD256A(7)
  __syncthreads();
  float lx = xl[0], ly = yl[0], lz = zl[0];
  if (t==0){ nx[0]=lx; ny[0]=ly; nz[0]=lz; }
  for (int i=1;i<SP1;i++){
    FPS1_ITER_BODY()
  }
  FPS_SAVE(0) FPS_SAVE(1) FPS_SAVE(2) FPS_SAVE(3) FPS_SAVE(4) FPS_SAVE(5) FPS_SAVE(6) FPS_SAVE(7)
}

// ---------------- KNN1 body (R20: direct-d tournament + DPP argmin) ----------------
#define KNN1_POISON(C) case C: d[C] = match ? 3.0e38f : d[C]; break;
DEVI void knn1_body(int wid, int lane){
  int b = wid >> 9;
  const float* xs = g_ws + OFF_XS + (size_t)b*NN;
  const float* ys = g_ws + OFF_YS + (size_t)b*NN;
  const float* zs = g_ws + OFF_ZS + (size_t)b*NN;
  const float* sq = g_ws + OFF_SSQ + (size_t)b*NN;
  float cx = g_ws[OFF_NX1X + wid], cy = g_ws[OFF_NX1Y + wid], cz = g_ws[OFF_NX1Z + wid];
  float sc = sq3(cx,cy,cz);
  float d[32];
  #pragma unroll
  for (int c=0;c<32;c++){
    int n = c*64 + lane;
    float x=xs[n], y=ys[n], z=zs[n];
    float dot = rn_add(rn_add(rn_mul(cx,x),rn_mul(cy,y)),rn_mul(cz,z));
    d[c] = rn_sub(rn_add(sc,sq[n]), rn_mul(2.f,dot));
  }
  int* out = (int*)(g_ws + OFF_KNN1) + (size_t)wid*16;
  for (int r=0;r<16;r++){
    float tv[16]; int tc[16];
    #pragma unroll
    for (int c=0;c<16;c++){
      float a = d[2*c];
      float e = d[2*c+1];
      bool cc = e < a;
      tv[c] = cc ? e : a; tc[c] = cc ? (2*c+1) : (2*c);
    }
    #pragma unroll
    for (int s=1; s<16; s<<=1){
      #pragma unroll
      for (int c=0;c<16;c+=2){
        if ((c % (2*s)) == 0 && c+s < 16){
          bool cc = tv[c+s] < tv[c];
          tv[c] = cc ? tv[c+s] : tv[c];
          tc[c] = cc ? tc[c+s] : tc[c];
        }
      }
    }
    float best = tv[0]; int bidx = tc[0]*64 + lane;   // bidx IS the point index
    WAVE_ARGMIN()                                     // lane 63 holds wave argmin
    int wbi = __builtin_amdgcn_readlane(bidx, 63);    // wave-uniform winner
    if (lane == 0) out[r] = wbi;
    bool match = (lane == (wbi & 63));
    switch ((wbi >> 6) & 31){
      KNN1_POISON(0)  KNN1_POISON(1)  KNN1_POISON(2)  KNN1_POISON(3)
      KNN1_POISON(4)  KNN1_POISON(5)  KNN1_POISON(6)  KNN1_POISON(7)
      KNN1_POISON(8)  KNN1_POISON(9)  KNN1_POISON(10) KNN1_POISON(11)
      KNN1_POISON(12) KNN1_POISON(13) KNN1_POISON(14) KNN1_POISON(15)
      KNN1_POISON(16) KNN1_POISON(17) KNN1_POISON(18) KNN1_POISON(19)
      KNN1_POISON(20) KNN1_POISON(21) KNN1_POISON(22) KNN1_POISON(23)
      KNN1_POISON(24) KNN1_POISON(25) KNN1_POISON(26) KNN1_POISON(27)
      KNN1_POISON(28) KNN1_POISON(29) KNN1_POISON(30) KNN1_POISON(31)
    }
  }
}

// ---------------- SA1 body (factored; bxx covers gids [16*bxx, 16*bxx+16)) ----------------
DEVI void sa1_body(int br, int bxx, float* w1s, float* b1s, short* Hh, short* Hl){
  const int t = threadIdx.x;
  const int wave = t>>6, lane = t&63, quad = lane>>4, l16 = lane&15;
  for (int i=t;i<384;i+=256) w1s[i] = g_ws[W1A + (size_t)br*384 + i];
  if (t<64) b1s[t] = g_ws[B1A + br*64 + t];
  __syncthreads();                                  // cross-wave (w1s/b1s) — keep
  const int* kn = (const int*)(g_ws + OFF_KNN1);
  const short* w2h = (const short*)(g_ws + OFF_W2ABH) + (size_t)br*128*64;
  const short* w2l = (const short*)(g_ws + OFF_W2ABL) + (size_t)br*128*64;
  const float* b2 = g_ws + B2A + br*128;
  for (int it=0; it<4; it++){
    int gid = bxx*16 + it*4 + wave;
    int b = gid >> 9;
    int idx = kn[(size_t)gid*16 + l16] & (NN-1);
    float cx = g_ws[OFF_NX1X+gid], cy = g_ws[OFF_NX1Y+gid], cz = g_ws[OFF_NX1Z+gid];
    size_t gl = (size_t)b*NN + idx;
    float x = g_ws[OFF_XS+gl], y = g_ws[OFF_YS+gl], z = g_ws[OFF_ZS+gl];
    float f0=x-cx, f1=y-cy, f2=z-cz;
    #pragma unroll
    for (int i=0;i<16;i++){
      int h = quad*16 + i;
      float acc = b1s[h];
      acc += f0*w1s[h*6+0] + f1*w1s[h*6+1] + f2*w1s[h*6+2]
           +  x*w1s[h*6+3] +  y*w1s[h*6+4] +  z*w1s[h*6+5];
      acc = fmaxf(acc, 0.f);
      unsigned short hi = f2bf(acc);
      Hh[wave*1152 + l16*72 + h] = (short)hi;
      Hl[wave*1152 + l16*72 + h] = (short)f2bf(acc - bfbits2f(hi));
    }
    // (no __syncthreads: Hh/Hl exchange is wave-local; lgkmcnt orders it)
    s16x8 ah[2], al[2];
    #pragma unroll
    for (int ks=0;ks<2;ks++){
      ah[ks] = *(const s16x8*)(&Hh[wave*1152 + l16*72 + ks*32 + quad*8]);
      al[ks] = *(const s16x8*)(&Hl[wave*1152 + l16*72 + ks*32 + quad*8]);
    }
    unsigned short* P1g = (unsigned short*)(g_ws + OFF_P1) + ((size_t)br*16384 + gid)*128;
    #pragma unroll
    for (int ni=0; ni<8; ni++){
      int o = ni*16 + l16;
      f32x4 acc = {0.f,0.f,0.f,0.f};
      #pragma unroll
      for (int ks=0; ks<2; ks++){
        s16x8 bh = *(const s16x8*)(w2h + (size_t)o*64 + ks*32 + quad*8);
        s16x8 bl = *(const s16x8*)(w2l + (size_t)o*64 + ks*32 + quad*8);
        mfma16(acc, ah[ks], bh);
        mfma16(acc, ah[ks], bl);
        mfma16(acc, al[ks], bh);
      }
      mfma_guard(acc);
      float vmax = fmaxf(fmaxf(acc[0],acc[1]), fmaxf(acc[2],acc[3]));
      vmax = fmaxf(vmax, __shfl_xor(vmax,16));
      vmax = fmaxf(vmax, __shfl_xor(vmax,32));
      if (quad==0) P1g[o] = f2bf(vmax + b2[o]);     // R24: bf16
    }
  }
}

// K2: fps1 iters [SP1,SP2) (blocks 0..31) + knn1 centers [0,160) (blocks 32..1311)
__global__ __launch_bounds__(256,1) void fps1B_knn1a_kernel(){
  const int t = threadIdx.x;
  if (blockIdx.x >= 32){
    int lin = ((blockIdx.x-32)*256 + t) >> 6;   // [0, 5120)
    int b = lin / 160, s = lin % 160;
    knn1_body(b*S1 + s, t & 63);
    return;
  }
  FPS1_BLOCK_SETUP()
  FPS_LD256B(0) FPS_LD256B(1) FPS_LD256B(2) FPS_LD256B(3) FPS_LD256B(4) FPS_LD256B(5) FPS_LD256B(6) FPS_LD256B(7)
  __syncthreads();
  float lx = nx[SP1-1], ly = ny[SP1-1], lz = nz[SP1-1];  // bits identical to segA's final state
  for (int i=SP1;i<SP2;i++){
    FPS1_ITER_BODY()
  }
  FPS_SAVE(0) FPS_SAVE(1) FPS_SAVE(2) FPS_SAVE(3) FPS_SAVE(4) FPS_SAVE(5) FPS_SAVE(6) FPS_SAVE(7)
}

// K3 (R28): fps1 iters [SP2,512) (0..31) + knn1 [160,336) (32..1439) + sa1 sblk 0..9 (1440..2399)
// Union smem: fps role uses 24.6KB xl/yl/zl+combine; sa1 role uses 20.2KB
// w1s/b1s/Hh/Hl. Aliasing one buffer keeps LDS_Block_Size ~24.6KB -> 6 blk/CU.
__global__ __launch_bounds__(256,1) void fps1C_knn1b_sa1a_kernel(){
  __shared__ __align__(16) char smem[3*NN*4 + 64];
  const int t = threadIdx.x;
  if (blockIdx.x >= 1440){
    int q = blockIdx.x - 1440;           // [0, 960) = 3 br x 32 b x 10 sblk
    int br = q / 320, rem = q % 320;
    int b = rem / 10, sblk = rem % 10;   // centers s <= 159 < 160 (knn1a done end-K2)
    float* w1s = (float*)smem;
    float* b1s = w1s + 384;
    short* Hh = (short*)(b1s + 64);
    short* Hl = Hh + 4608;
    sa1_body(br, b*32 + sblk, w1s, b1s, Hh, Hl);
    return;
  }
  if (blockIdx.x >= 32){
    int lin = ((blockIdx.x-32)*256 + t) >> 6;   // [0, 5632)
    int b = lin / 176, s = 160 + lin % 176;
    knn1_body(b*S1 + s, t & 63);
    return;
  }
  FPS1_BLOCK_SETUP_U(smem)
  FPS_LD256B(0) FPS_LD256B(1) FPS_LD256B(2) FPS_LD256B(3) FPS_LD256B(4) FPS_LD256B(5) FPS_LD256B(6) FPS_LD256B(7)
  __syncthreads();
  float lx = nx[SP2-1], ly = ny[SP2-1], lz = nz[SP2-1];  // bits identical to segB's final state
  for (int i=SP2;i<S1;i++){
    FPS1_ITER_BODY()
  }
}

// K4: fps2 (0..31) + knn1 centers [336,512) (32..1439) + sa1 sblk 10..20 (1440..2495)
__global__ __launch_bounds__(256) void fps2_knn1c_sa1a_kernel(){
  __shared__ float xl[S1], yl[S1], zl[S1];
  __shared__ float w1s[384];
  __shared__ float b1s[64];
  __shared__ __align__(16) short Hh[4*16*72];
  __shared__ __align__(16) short Hl[4*16*72];
  const int t = threadIdx.x;
  if (blockIdx.x >= 1440){
    int q = blockIdx.x - 1440;           // [0, 1056) = 3 br x 32 b x 11 sblk
    int br = q / 352, rem = q % 352;
    int b = rem / 11, sblk = 10 + rem % 11;  // centers s in [160,336) (knn1b done end-K3)
    sa1_body(br, b*32 + sblk, w1s, b1s, Hh, Hl);
    return;
  }
  if (blockIdx.x >= 32){
    int lin = ((blockIdx.x-32)*256 + t) >> 6;   // [0, 5632)
    int b = lin / 176, s = 336 + lin % 176;
    knn1_body(b*S1 + s, t & 63);
    return;
  }
  if (t >= 64) return;
  const int b = blockIdx.x;
  const float* xs = g_ws + OFF_NX1X + (size_t)b*S1;
  const float* ys = g_ws + OFF_NX1Y + (size_t)b*S1;
  const float* zs = g_ws + OFF_NX1Z + (size_t)b*S1;
  float* nx = g_ws + OFF_NX2X + (size_t)b*S2;
  float* ny = g_ws + OFF_NX2Y + (size_t)b*S2;
  float* nz = g_ws + OFF_NX2Z + (size_t)b*S2;
  FPS_DECL(0) FPS_DECL(1) FPS_DECL(2) FPS_DECL(3) FPS_DECL(4) FPS_DECL(5) FPS_DECL(6) FPS_DECL(7)
  FPS_LD64(0) FPS_LD64(1) FPS_LD64(2) FPS_LD64(3) FPS_LD64(4) FPS_LD64(5) FPS_LD64(6) FPS_LD64(7)
  float lx = xl[0], ly = yl[0], lz = zl[0];
  if (t==0){ nx[0]=lx; ny[0]=ly; nz[0]=lz; }
  for (int i=1;i<S2;i++){
    FPS_UPD(0) FPS_UPD(1) FPS_UPD(2) FPS_UPD(3) FPS_UPD(4) FPS_UPD(5) FPS_UPD(6) FPS_UPD(7)
    FPS_T1(0,0,1) FPS_T1(1,2,3) FPS_T1(2,4,5) FPS_T1(3,6,7)
    FPS_T2(0,1) FPS_T2(2,3)
    FPS_T2(0,2)
    float best = v0; int bidx = q0*64 + t;
    WAVE_ARGMAX()
    int gidx = __builtin_amdgcn_readlane(bidx, 63);
    lx = xl[gidx]; ly = yl[gidx]; lz = zl[gidx];
    if (t==0){ nx[i]=lx; ny[i]=ly; nz[i]=lz; }
  }
}

// ---------------- KNN2 body (R20: direct-d tournament + DPP argmin) ----------------
#define KNN2_POISON(C) case C: d[C] = match ? 3.0e38f : d[C]; break;
DEVI void knn2_body(int wid, int lane){
  int b = wid >> 7;
  const float* xs = g_ws + OFF_NX1X + (size_t)b*S1;
  const float* ys = g_ws + OFF_NX1Y + (size_t)b*S1;
  const float* zs = g_ws + OFF_NX1Z + (size_t)b*S1;
  float cx = g_ws[OFF_NX2X + wid], cy = g_ws[OFF_NX2Y + wid], cz = g_ws[OFF_NX2Z + wid];
  float sc = sq3(cx,cy,cz);
  float d[8];
  #pragma unroll
  for (int c=0;c<8;c++){
    int n = c*64 + lane;
    float x=xs[n], y=ys[n], z=zs[n];
    float sx = sq3(x,y,z);
    float dot = rn_add(rn_add(rn_mul(cx,x),rn_mul(cy,y)),rn_mul(cz,z));
    d[c] = rn_sub(rn_add(sc,sx), rn_mul(2.f,dot));
  }
  int* out = (int*)(g_ws + OFF_KNN2) + (size_t)wid*48;
  for (int r=0;r<48;r++){
    float tv[4]; int tc[4];
    #pragma unroll
    for (int c=0;c<4;c++){
      float a = d[2*c];
      float e = d[2*c+1];
      bool cc = e < a;
      tv[c] = cc ? e : a; tc[c] = cc ? (2*c+1) : (2*c);
    }
    { bool cc = tv[1] < tv[0]; tv[0] = cc?tv[1]:tv[0]; tc[0] = cc?tc[1]:tc[0]; }
    { bool cc = tv[3] < tv[2]; tv[2] = cc?tv[3]:tv[2]; tc[2] = cc?tc[3]:tc[2]; }
    { bool cc = tv[2] < tv[0]; tv[0] = cc?tv[2]:tv[0]; tc[0] = cc?tc[2]:tc[0]; }
    float best = tv[0]; int bidx = tc[0]*64 + lane;   // point index in [0,512)
    WAVE_ARGMIN()
    int wbi = __builtin_amdgcn_readlane(bidx, 63);
    if (lane == 0) out[r] = wbi;
    bool match = (lane == (wbi & 63));
    switch ((wbi >> 6) & 7){
      KNN2_POISON(0) KNN2_POISON(1) KNN2_POISON(2) KNN2_POISON(3)
      KNN2_POISON(4) KNN2_POISON(5) KNN2_POISON(6) KNN2_POISON(7)
    }
  }
}

// K5: knn2 (blocks 0..1023) + sa1 sblk 21..31 (blocks 1024..2079)
__global__ __launch_bounds__(256) void knn2_sa1b_kernel(){
  __shared__ float w1s[384];
  __shared__ float b1s[64];
  __shared__ __align__(16) short Hh[4*16*72];
  __shared__ __align__(16) short Hl[4*16*72];
  const int t = threadIdx.x;
  if (blockIdx.x < 1024){
    knn2_body((blockIdx.x*256 + t) >> 6, t & 63);
    return;
  }
  int q = blockIdx.x - 1024;              // [0, 1056) = 3 br x 32 b x 11 sblk
  int br = q / 352, rem = q % 352;
  int b = rem / 11, sblk = 21 + rem % 11;
  sa1_body(br, b*32 + sblk, w1s, b1s, Hh, Hl);
}

// ---------------- SA2 (all branches) -> X3 bf16 hi/lo ----------------
// R31: revert R30's restructure (regressed: conflicts weren't binding). Keep
// exact R29 per-center math but batch G centers per block (G*K = 64 rows for
// br0/br1) so each layer1/layer2 weight fetch feeds R/16 m-tiles instead of
// K/16. Blocks 12288 -> 7168; weight L2 traffic 1.25 -> 0.73 GB. Per-center
// MFMA chains / fmax order / writes identical -> bit-exact.
template<int K, int G>
DEVI void sa2_body(int br, int g2base, short* Xb, short* Hb, float* ctr, int* idxs){
  constexpr int R = K*G;          // total rows in block
  constexpr int MT = R/16;        // m-tiles
  constexpr int CT = K/16;        // m-tiles per center
  const int b = g2base >> 7;
  const int t = threadIdx.x;
  const int wave = t >> 6, lane = t & 63, quad = lane >> 4, l16 = lane & 15;
  if (t < R){
    int g = t / K;
    const int* kn2 = (const int*)(g_ws + OFF_KNN2) + (size_t)(g2base + g)*48;
    idxs[t] = kn2[t - g*K] & (S1-1);
  }
  if (t < 3*G){
    int g = t/3, d = t - g*3;
    ctr[t] = g_ws[(d==0?OFF_NX2X:(d==1?OFF_NX2Y:OFF_NX2Z)) + g2base + g];
  }
  __syncthreads();
  const unsigned short* p1b = (const unsigned short*)(g_ws + OFF_P1) + (size_t)br*16384*128;
  const int grp = t >> 5, gl = t & 31;
  for (int k = grp; k < R; k += 8){
    int idx = idxs[k];
    const unsigned short* row = p1b + ((size_t)b*S1 + idx)*128;
    unsigned long long w = *(const unsigned long long*)(row + gl*4);   // 4 bf16, 8B aligned
    short* dst = &Xb[k*168 + 3 + gl*4];
    dst[0] = (short)(w & 0xFFFF);
    dst[1] = (short)((w >> 16) & 0xFFFF);
    dst[2] = (short)((w >> 32) & 0xFFFF);
    dst[3] = (short)((w >> 48) & 0xFFFF);
    Xb[k*168 + 131 + gl] = 0;
    if (gl < 5)  Xb[k*168 + 163 + gl] = 0;
  }
  if (t < R){
    int g = t / K;
    int idx = idxs[t];
    float c0 = g_ws[OFF_NX1X + (size_t)b*S1 + idx] - ctr[g*3+0];
    float c1 = g_ws[OFF_NX1Y + (size_t)b*S1 + idx] - ctr[g*3+1];
    float c2 = g_ws[OFF_NX1Z + (size_t)b*S1 + idx] - ctr[g*3+2];
    Xb[t*168+0] = (short)f2bf(c0);
    Xb[t*168+1] = (short)f2bf(c1);
    Xb[t*168+2] = (short)f2bf(c2);
  }
  __syncthreads();
  {
    const short* w1bf = (const short*)(g_ws + OFF_W1BF) + (size_t)br*128*160;
    const float* b1 = g_ws + B1B + br*128;
    for (int ni = wave; ni < 8; ni += 4){
      int h = ni*16 + l16;
      s16x8 bfr[5];
      #pragma unroll
      for (int ks=0;ks<5;ks++) bfr[ks] = *(const s16x8*)(w1bf + (size_t)h*160 + ks*32 + quad*8);
      float bias = b1[h];
      #pragma unroll
      for (int m=0; m<MT; m++){
        f32x4 acc = {0.f,0.f,0.f,0.f};
        #pragma unroll
        for (int ks=0;ks<5;ks++){
          s16x8 a = *(const s16x8*)(&Xb[(m*16 + l16)*168 + ks*32 + quad*8]);
          mfma16(acc, a, bfr[ks]);
        }
        mfma_guard(acc);
        #pragma unroll
        for (int r=0;r<4;r++){
          int row = m*16 + quad*4 + r;
          float hv = fmaxf(acc[r] + bias, 0.f);
          Hb[row*136 + ni*16 + l16] = (short)f2bf(hv);
        }
      }
    }
  }
  __syncthreads();
  {
    const short* w2bf = (const short*)(g_ws + OFF_W2BF) + (size_t)br*256*128;
    const float* b2 = g_ws + B2B + br*256;
    unsigned short* xh = (unsigned short*)(g_ws + OFF_X3BH);
    unsigned short* xlo = (unsigned short*)(g_ws + OFF_X3BL);
    for (int ni = wave; ni < 16; ni += 4){
      int o = ni*16 + l16;
      s16x8 bfr[4];
      #pragma unroll
      for (int ks=0;ks<4;ks++) bfr[ks] = *(const s16x8*)(w2bf + (size_t)o*128 + ks*32 + quad*8);
      float vm[G];
      #pragma unroll
      for (int g=0;g<G;g++) vm[g] = -3.4e38f;
      #pragma unroll
      for (int m=0; m<MT; m++){
        f32x4 acc = {0.f,0.f,0.f,0.f};
        #pragma unroll
        for (int ks=0;ks<4;ks++){
          s16x8 a = *(const s16x8*)(&Hb[(m*16 + l16)*136 + ks*32 + quad*8]);
          mfma16(acc, a, bfr[ks]);
        }
        mfma_guard(acc);
        #pragma unroll
        for (int r=0;r<4;r++) vm[m/CT] = fmaxf(vm[m/CT], acc[r]);
      }
      #pragma unroll
      for (int g=0;g<G;g++){
        float v = vm[g];
        v = fmaxf(v, __shfl_xor(v, 16));
        v = fmaxf(v, __shfl_xor(v, 32));
        if (quad == 0){
          size_t rowg = (size_t)(br*4096 + g2base + g)*288;
          float hv = v + b2[o];
          unsigned short hi = f2bf(hv);
          xh[rowg + 3 + o] = hi;
          xlo[rowg + 3 + o] = f2bf(hv - bfbits2f(hi));
        }
      }
    }
    unsigned short* xh2 = (unsigned short*)(g_ws + OFF_X3BH);
    unsigned short* xlo2 = (unsigned short*)(g_ws + OFF_X3BL);
    #pragma unroll
    for (int g=0;g<G;g++){
      size_t rowg = (size_t)(br*4096 + g2base + g)*288;
      if (t < 3){
        float cv = ctr[g*3+t];
        unsigned short hi = f2bf(cv);
        xh2[rowg + t] = hi; xlo2[rowg + t] = f2bf(cv - bfbits2f(hi));
      }
      if (t >= 3 && t < 32){ xh2[rowg + 256 + t] = 0; xlo2[rowg + 256 + t] = 0; }
    }
  }
}

// R29 XCD-chunked remap kept (P1 L2 locality; FETCH 40->8MB). R31 grid:
// per XCD: br0 128 blocks (G=4), br1 256 (G=2), br2 512 (G=1) = 896; x8 = 7168.
__global__ __launch_bounds__(256) void sa2_all_kernel(){
  __shared__ __align__(16) short Xb[64*168];
  __shared__ __align__(16) short Hb[64*136];
  __shared__ float ctr[12];
  __shared__ int idxs[64];
  int xcd = blockIdx.x & 7;
  int idx = blockIdx.x >> 3;            // [0, 896)
  if (idx < 128){
    int bloc = idx >> 5, g2o = (idx & 31) << 2;
    int b = xcd*4 + bloc;
    sa2_body<16,4>(0, b*128 + g2o, Xb, Hb, ctr, idxs);
  } else if (idx < 384){
    int j = idx - 128;
    int bloc = j >> 6, g2o = (j & 63) << 1;
    int b = xcd*4 + bloc;
    sa2_body<32,2>(1, b*128 + g2o, Xb, Hb, ctr, idxs);
  } else {
    int j = idx - 384;
    int bloc = j >> 7, g2o = j & 127;
    int b = xcd*4 + bloc;
    sa2_body<48,1>(2, b*128 + g2o, Xb, Hb, ctr, idxs);
  }
}

// ---------------- SA3 layer1 via MFMA (hi/lo): 288 -> 512 relu ----------------
__global__ __launch_bounds__(256) void sa3l1_mfma_kernel(){
  const int br = blockIdx.y; const int r0 = blockIdx.x*32;
  const int t = threadIdx.x;
  const int wave = t >> 6, lane = t & 63, quad = lane >> 4, l16 = lane & 15;
  const short* xh = (const short*)(g_ws + OFF_X3BH) + (size_t)(br*4096 + r0)*288;
  const short* xl = (const short*)(g_ws + OFF_X3BL) + (size_t)(br*4096 + r0)*288;
  const short* wh = (const short*)(g_ws + OFF_W1CBH) + (size_t)br*512*288;
  const short* wl = (const short*)(g_ws + OFF_W1CBL) + (size_t)br*512*288;
  const float* bias = g_ws + B1C + br*512;
  unsigned short* hh = (unsigned short*)(g_ws + OFF_H3BH) + (size_t)(br*4096 + r0)*512;
  unsigned short* hl = (unsigned short*)(g_ws + OFF_H3BL) + (size_t)(br*4096 + r0)*512;
  f32x4 acc[2][8];
  #pragma unroll
  for (int m=0;m<2;m++)
    #pragma unroll
    for (int ni=0;ni<8;ni++) acc[m][ni] = (f32x4){0.f,0.f,0.f,0.f};
  for (int ks=0; ks<9; ks++){
    s16x8 ah[2], al[2];
    #pragma unroll
    for (int m=0;m<2;m++){
      ah[m] = *(const s16x8*)(xh + (size_t)(m*16+l16)*288 + ks*32 + quad*8);
      al[m] = *(const s16x8*)(xl + (size_t)(m*16+l16)*288 + ks*32 + quad*8);
    }
    #pragma unroll
    for (int ni=0;ni<8;ni++){
      int n = wave*128 + ni*16 + l16;
      s16x8 bh = *(const s16x8*)(wh + (size_t)n*288 + ks*32 + quad*8);
      s16x8 bl = *(const s16x8*)(wl + (size_t)n*288 + ks*32 + quad*8);
      #pragma unroll
      for (int m=0;m<2;m++){
        mfma16(acc[m][ni], ah[m], bh);
        mfma16(acc[m][ni], ah[m], bl);
        mfma16(acc[m][ni], al[m], bh);
      }
    }
  }
  mfma_guard(acc[0][0]);
  #pragma unroll
  for (int m=0;m<2;m++){
    #pragma unroll
    for (int ni=0;ni<8;ni++){
      int col = wave*128 + ni*16 + l16;
      float bs = bias[col];
      #pragma unroll
      for (int r=0;r<4;r++){
        int row = m*16 + quad*4 + r;
        float hv = fmaxf(acc[m][ni][r] + bs, 0.f);
        unsigned short hi = f2bf(hv);
        hh[(size_t)row*512 + col] = hi;
        hl[(size_t)row*512 + col] = f2bf(hv - bfbits2f(hi));
      }
    }
  }
}

// ---------------- SA3 layer2 via MFMA (hi/lo): 512 -> 512, partial max ----------------
__global__ __launch_bounds__(256) void sa3l2_mfma_kernel(){
  const int br = blockIdx.y; const int b = blockIdx.x>>2; const int part = blockIdx.x&3;
  const int t = threadIdx.x;
  const int wave = t >> 6, lane = t & 63, quad = lane >> 4, l16 = lane & 15;
  const int row0 = b*128 + part*32;
  const short* ahp = (const short*)(g_ws + OFF_H3BH) + (size_t)(br*4096 + row0)*512;
  const short* alp = (const short*)(g_ws + OFF_H3BL) + (size_t)(br*4096 + row0)*512;
  const short* wh = (const short*)(g_ws + OFF_W2CBH) + (size_t)br*512*512;
  const short* wl = (const short*)(g_ws + OFF_W2CBL) + (size_t)br*512*512;
  f32x4 acc[2][8];
  #pragma unroll
  for (int m=0;m<2;m++)
    #pragma unroll
    for (int ni=0;ni<8;ni++) acc[m][ni] = (f32x4){0.f,0.f,0.f,0.f};
  for (int ks=0; ks<16; ks++){
    s16x8 ah[2], al[2];
    #pragma unroll
    for (int m=0;m<2;m++){
      ah[m] = *(const s16x8*)(ahp + (size_t)(m*16+l16)*512 + ks*32 + quad*8);
      al[m] = *(const s16x8*)(alp + (size_t)(m*16+l16)*512 + ks*32 + quad*8);
    }
    #pragma unroll
    for (int ni=0;ni<8;ni++){
      int n = wave*128 + ni*16 + l16;
      s16x8 bh = *(const s16x8*)(wh + (size_t)n*512 + ks*32 + quad*8);
      s16x8 bl = *(const s16x8*)(wl + (size_t)n*512 + ks*32 + quad*8);
      #pragma unroll
      for (int m=0;m<2;m++){
        mfma16(acc[m][ni], ah[m], bh);
        mfma16(acc[m][ni], ah[m], bl);
        mfma16(acc[m][ni], al[m], bh);
      }
    }
  }
  mfma_guard(acc[0][0]);
  #pragma unroll
  for (int ni=0;ni<8;ni++){
    float vmax = -3.4e38f;
    #pragma unroll
    for (int m=0;m<2;m++)
      #pragma unroll
      for (int r=0;r<4;r++) vmax = fmaxf(vmax, acc[m][ni][r]);
    vmax = fmaxf(vmax, __shfl_xor(vmax, 16));
    vmax = fmaxf(vmax, __shfl_xor(vmax, 32));
    if (quad == 0){
      int col = wave*128 + ni*16 + l16;
      g_ws[OFF_O3P + (((size_t)br*BB + b)*4 + part)*512 + col] = vmax;
    }
  }
}

// ---------------- FC head + combine fused (f32 out) ----------------
__global__ __launch_bounds__(256) void fc_kernel(float* __restrict__ out, int out_size){
  int br = blockIdx.x >> 5; int b = blockIdx.x & 31; int t = threadIdx.x;
  __shared__ float xin[512]; __shared__ float x1s[256];
  const float* o3p = g_ws + OFF_O3P + (((size_t)br*BB + b)*4)*512;
  const float* b2c = g_ws + B2C + br*512;
  #pragma unroll
  for (int k=0;k<2;k++){
    int o = t + k*256;
    float m = fmaxf(fmaxf(o3p[o], o3p[512+o]), fmaxf(o3p[1024+o], o3p[1536+o]));
    m += b2c[o];
    xin[o] = m;
    int oi = 3*BB*128 + ((br*BB + b)*512) + o;
    if (oi < out_size) out[oi] = m;
  }
  __syncthreads();
  const float s = (float)(1.0 / sqrt(1.0 + 1e-5));
  {
    const float4* wp = (const float4*)(g_ws + FW1 + ((size_t)br*256 + t)*512);
    const float4* xp = (const float4*)xin;
    float acc = 0.f;
    #pragma unroll 8
    for (int q=0;q<128;q++){ float4 w4=wp[q], x4=xp[q]; acc += w4.x*x4.x + w4.y*x4.y + w4.z*x4.z + w4.w*x4.w; }
    acc = (acc + g_ws[FB1 + br*256+t]) * s;
    acc = g_ws[FG1+br*256+t]*acc + g_ws[FBE1+br*256+t];
    x1s[t] = fmaxf(acc, 0.f);
  }
  __syncthreads();
  if (t < 128){
    const float4* wp = (const float4*)(g_ws + FW2 + ((size_t)br*128 + t)*256);
    const float4* xp = (const float4*)x1s;
    float acc=0.f;
    #pragma unroll 8
    for (int q=0;q<64;q++){ float4 w4=wp[q], x4=xp[q]; acc += w4.x*x4.x + w4.y*x4.y + w4.z*x4.z + w4.w*x4.w; }
    acc = (acc + g_ws[FB2+br*128+t])*s;
    acc = g_ws[FG2+br*128+t]*acc + g_ws[FBE2+br*128+t];
    int oi = ((size_t)br*BB + b)*128 + t;
    if (oi < out_size) out[oi] = fmaxf(acc,0.f);
  }
}

// ---------------- launch (R31: sa2 center-batching for weight amortization) ----------------
extern "C" void kernel_launch(void* const* d_in, const int* in_sizes, int n_in,
                              void* d_out, int out_size, void* d_ws, size_t ws_size,
                              hipStream_t stream) {
  (void)d_ws; (void)ws_size;
  if (n_in < 21) return;
  if (in_sizes[0] != BB*3*NN) return;
  float* out = (float*)d_out;

  ParamPtrs pp;
  for (int i=0;i<20;i++) pp.p[i] = d_in[i+1];

  init_detect_kernel<<<1,256,0,stream>>>(d_in[0]);
  cvtprep_kernel<<<768,256,0,stream>>>(pp, d_in[0], 0);
  scan_check_kernel<<<256,256,0,stream>>>();
  resolve_flip_kernel<<<1,64,0,stream>>>();
  cvtprep_kernel<<<768,256,0,stream>>>(pp, d_in[0], 1);   // gated on g_flip

  fps1A_cvt_kernel<<<32+256,256,0,stream>>>();            // fps1 [1,171) + cvt_bf16
  fps1B_knn1a_kernel<<<32+1280,256,0,stream>>>();         // fps1 [171,342) || knn1 [0,160)
  fps1C_knn1b_sa1a_kernel<<<32+1408+960,256,0,stream>>>();// fps1 [342,512) || knn1 [160,336) || sa1 sblk 0..9
  fps2_knn1c_sa1a_kernel<<<32+1408+1056,256,0,stream>>>();// fps2 || knn1 [336,512) || sa1 sblk 10..20
  knn2_sa1b_kernel<<<1024+1056,256,0,stream>>>();         // knn2 || sa1 sblk 21..31
  sa2_all_kernel<<<7168,256,0,stream>>>();                // XCD-chunked + G-center batching (R31)

  sa3l1_mfma_kernel<<<dim3(128,3),256,0,stream>>>();
  sa3l2_mfma_kernel<<<dim3(128,3),256,0,stream>>>();
  fc_kernel<<<96,256,0,stream>>>(out, out_size);          // combine fused in
}